// Round 3
// baseline (619.579 us; speedup 1.0000x reference)
//
#include <hip/hip_runtime.h>
#include <math.h>

typedef unsigned int u32;
typedef unsigned short u16;
typedef __attribute__((ext_vector_type(8))) short bf16x8;
typedef __attribute__((ext_vector_type(4))) float f32x4;

#define NHEADS 8
#define HH 24
#define WW 24
#define HW 576
#define CS 256        // channels per group
#define CHD 32        // channels per head
#define NN 2304       // HW * NGROUPS
#define NGROUPS 4
#define TOPK 1843     // int(2304 * 0.8)
#define DIM 1024
#define EPSN 1e-12f
#define PSTR 2312     // P row stride in bf16 elems (rows 16B-aligned)

__device__ __forceinline__ unsigned fkey(float f) {
    unsigned u = __float_as_uint(f);
    return u ^ ((u >> 31) ? 0xFFFFFFFFu : 0x80000000u);  // monotonic map
}
__device__ __forceinline__ float fkey_inv(unsigned k) {
    return __uint_as_float((k & 0x80000000u) ? (k ^ 0x80000000u) : ~k);
}
__device__ __forceinline__ u16 f2bf(float f) {          // RNE fp32->bf16
    unsigned u = __float_as_uint(f);
    return (u16)((u + 0x7FFFu + ((u >> 16) & 1u)) >> 16);
}

// ---------------------------------------------------------------------------
// Kernel 1: fused group-mix (w_qkv) + depthwise 3x3 conv, scatter to head
// layout q/k[h][c][n] fp32 and v[h][c][n] bf16;  n = (hh*24+ww)*4 + t
// ---------------------------------------------------------------------------
__global__ __launch_bounds__(256) void qkv_conv_kernel(
    const float* __restrict__ x, const float* __restrict__ w_qkv,
    const float* __restrict__ w_dw,
    float* __restrict__ qb, float* __restrict__ kb, u16* __restrict__ vb16)
{
    __shared__ float xp[NGROUPS][26][26];
    __shared__ float wq[48];
    __shared__ float wd[108];
    int c = blockIdx.x;          // 0..255
    int tid = threadIdx.x;

    for (int i = tid; i < NGROUPS * 26 * 26; i += 256) ((float*)xp)[i] = 0.f;
    if (tid < 48) wq[tid] = w_qkv[tid];
    if (tid < 108) wd[tid] = w_dw[tid];
    __syncthreads();
    for (int i = tid; i < NGROUPS * HW; i += 256) {
        int t = i / HW, p = i % HW;
        int hh = p / WW, ww = p % WW;
        xp[t][hh + 1][ww + 1] = x[(size_t)(t * CS + c) * HW + p];
    }
    __syncthreads();

    int hd = c >> 5, ch = c & 31;
    for (int p = tid; p < HW; p += 256) {
        int hh = p / WW, ww = p % WW;
        float res[12];
        #pragma unroll
        for (int s = 0; s < 12; ++s) {
            float acc = 0.f;
            #pragma unroll
            for (int t = 0; t < NGROUPS; ++t) {
                float cv = 0.f;
                #pragma unroll
                for (int dh = 0; dh < 3; ++dh)
                    #pragma unroll
                    for (int dw = 0; dw < 3; ++dw)
                        cv += xp[t][hh + dh][ww + dw] * wd[s * 9 + dh * 3 + dw];
                acc += wq[s * 4 + t] * cv;
            }
            res[s] = acc;
        }
        #pragma unroll
        for (int tt = 0; tt < 4; ++tt) {
            int n = p * 4 + tt;
            size_t off = ((size_t)hd * CHD + ch) * NN + n;
            qb[off] = res[tt];
            kb[off] = res[4 + tt];
            vb16[off] = f2bf(res[8 + tt]);
        }
    }
}

// ---------------------------------------------------------------------------
// Kernel 2a: per-(h,c) L2 norm reciprocal for q (b<256) and k (b>=256)
// ---------------------------------------------------------------------------
__global__ __launch_bounds__(256) void norm_scale_kernel(
    const float* __restrict__ qb, const float* __restrict__ kb,
    float* __restrict__ scales)
{
    __shared__ float redf[5];
    int b = blockIdx.x;          // 0..511
    const float* rowp = ((b < 256) ? qb : kb) + (size_t)(b & 255) * NN;
    int tid = threadIdx.x;
    float ss = 0.f;
    for (int i = tid; i < NN; i += 256) { float v = rowp[i]; ss += v * v; }
    for (int off = 32; off > 0; off >>= 1) ss += __shfl_down(ss, off);
    int wid = tid >> 6, lane = tid & 63;
    if (lane == 0) redf[wid] = ss;
    __syncthreads();
    if (tid == 0)
        scales[b] = 1.f / fmaxf(sqrtf(redf[0] + redf[1] + redf[2] + redf[3]), EPSN);
}

// ---------------------------------------------------------------------------
// Kernel 2b: transpose+scale+cast q,k: [h][c][n] fp32 -> [h][n][c] bf16
// ---------------------------------------------------------------------------
__global__ __launch_bounds__(256) void transpose_cast_kernel(
    const float* __restrict__ qb, const float* __restrict__ kb,
    const float* __restrict__ scales,
    u16* __restrict__ Qt, u16* __restrict__ Kt)
{
    __shared__ float tile[32][33];
    int ntile = blockIdx.x;        // 0..71
    int h = blockIdx.y;            // 0..7
    int which = blockIdx.z;        // 0=q 1=k
    const float* src = which ? kb : qb;
    const float* scl = scales + which * 256;
    u16* dst = which ? Kt : Qt;
    int tid = threadIdx.x;
    int n0 = ntile * 32;
    #pragma unroll
    for (int cc = 0; cc < 32; cc += 8) {
        int c = cc + (tid >> 5);
        tile[c][tid & 31] = src[(size_t)(h * CHD + c) * NN + n0 + (tid & 31)]
                            * scl[h * CHD + c];
    }
    __syncthreads();
    int cgrp = tid & 7, nrow = tid >> 3;
    #pragma unroll
    for (int c0 = 0; c0 < 32; c0 += 16) {
        int c = c0 + cgrp * 2;
        u16 v0 = f2bf(tile[c][nrow]);
        u16 v1 = f2bf(tile[c + 1][nrow]);
        ushort2 v; v.x = v0; v.y = v1;
        *(ushort2*)(dst + ((size_t)h * NN + n0 + nrow) * CHD + c) = v;
    }
}

// ---------------------------------------------------------------------------
// Kernel 3: MFMA attention. 1 block = (head, 16 rows). 512 threads = 8 waves.
// Wave w owns columns [w*288, (w+1)*288). Scores in regs (72 keys/lane).
// Exact top-K select via shared-range histogram + candidate resolution.
// ---------------------------------------------------------------------------
__global__ __launch_bounds__(512) void attn_mfma_kernel(
    const u16* __restrict__ Qt, const u16* __restrict__ Kt,
    const u16* __restrict__ Vb, const float* __restrict__ temp,
    float* __restrict__ aout)
{
    extern __shared__ char smem[];
    u16* P       = (u16*)smem;                  // [16][PSTR] bf16   (73984 B)
    u32* hist    = (u32*)(smem + 73984);        // [16][256]         (16384 B)
    float* pvred = (float*)(smem + 73984);      // alias [8][32][16] (16384 B)
    u32* candk   = (u32*)(smem + 90368);        // [16][64]          (4096 B)
    u32* sb      = (u32*)(smem + 94464);        // small arrays
    u32* candCnt = sb;            // [16]
    u32* tieCnt  = sb + 16;       // [16]
    u32* rowKmax = sb + 32;       // [16]
    u32* TkeyA   = sb + 48;       // [16]
    u32* tieTakeA= sb + 64;       // [16]
    u32* eqCntA  = sb + 80;       // [16]
    int* cutA    = (int*)(sb + 96);  // [16]
    u32* kloA    = sb + 112;      // [16]
    u32* khiA    = sb + 128;      // [16]
    u32* remKA   = sb + 144;      // [16]
    u32* cntA    = sb + 160;      // [16]
    u32* stateA  = sb + 176;      // [16] 0=narrow 1=bin-resolved 2=T-resolved
    float* denomF= (float*)(sb + 192); // [16]
    u32* sc      = sb + 208;      // [0]=tileMin [1]=shift [2]=anyflag

    int tid = threadIdx.x;
    int lane = tid & 63;
    int w = tid >> 6;             // wave 0..7
    int q = lane >> 4;            // lane quarter 0..3
    int cI = lane & 15;           // lane column-in-tile
    int bid = blockIdx.x;
    int h = bid / 144;
    int n0 = (bid % 144) * 16;

    if (tid < 16) {
        rowKmax[tid] = 0u; candCnt[tid] = 0u; tieCnt[tid] = 0u;
        remKA[tid] = TOPK; stateA[tid] = 0u; cutA[tid] = NN - 1;
        denomF[tid] = 0.f;
    }
    if (tid == 0) sc[0] = 0xFFFFFFFFu;
    __syncthreads();

    const u16* Qth = Qt + (size_t)h * NN * CHD;
    const u16* Kth = Kt + (size_t)h * NN * CHD;
    const u16* Vbh = Vb + (size_t)h * CHD * NN;
    float ts = temp[h];

    // ---- QK^T via MFMA: 18 tiles of 16 cols; keys kept in registers ----
    u32 kk[18][4];
    {
        bf16x8 afrag = *(const bf16x8*)(Qth + (size_t)(n0 + cI) * CHD + q * 8);
        u32 lmax0 = 0, lmax1 = 0, lmax2 = 0, lmax3 = 0;
        u32 lmin = 0xFFFFFFFFu;
        #pragma unroll
        for (int t = 0; t < 18; ++t) {
            int m0 = w * 288 + t * 16;
            bf16x8 bfrag = *(const bf16x8*)(Kth + (size_t)(m0 + cI) * CHD + q * 8);
            f32x4 z = {0.f, 0.f, 0.f, 0.f};
            f32x4 acc = __builtin_amdgcn_mfma_f32_16x16x32_bf16(afrag, bfrag, z, 0, 0, 0);
            u32 k0 = fkey(acc[0] * ts); kk[t][0] = k0; lmax0 = max(lmax0, k0); lmin = min(lmin, k0);
            u32 k1 = fkey(acc[1] * ts); kk[t][1] = k1; lmax1 = max(lmax1, k1); lmin = min(lmin, k1);
            u32 k2 = fkey(acc[2] * ts); kk[t][2] = k2; lmax2 = max(lmax2, k2); lmin = min(lmin, k2);
            u32 k3 = fkey(acc[3] * ts); kk[t][3] = k3; lmax3 = max(lmax3, k3); lmin = min(lmin, k3);
        }
        #pragma unroll
        for (int mk = 1; mk < 16; mk <<= 1) {
            lmax0 = max(lmax0, (u32)__shfl_xor((int)lmax0, mk));
            lmax1 = max(lmax1, (u32)__shfl_xor((int)lmax1, mk));
            lmax2 = max(lmax2, (u32)__shfl_xor((int)lmax2, mk));
            lmax3 = max(lmax3, (u32)__shfl_xor((int)lmax3, mk));
        }
        #pragma unroll
        for (int mk = 1; mk < 64; mk <<= 1)
            lmin = min(lmin, (u32)__shfl_xor((int)lmin, mk));
        if (cI == 0) {
            atomicMax(&rowKmax[4 * q + 0], lmax0);
            atomicMax(&rowKmax[4 * q + 1], lmax1);
            atomicMax(&rowKmax[4 * q + 2], lmax2);
            atomicMax(&rowKmax[4 * q + 3], lmax3);
        }
        if (lane == 0) atomicMin(&sc[0], lmin);
    }
    __syncthreads();

    // ---- zero hist; compute shared shift ----
    for (int i = tid; i < 16 * 256; i += 512) hist[i] = 0u;
    if (tid == 0) {
        u32 tmax = 0;
        for (int r = 0; r < 16; ++r) tmax = max(tmax, rowKmax[r]);
        u32 d = tmax - sc[0];
        sc[1] = (d <= 255u) ? 0u : (u32)(24 - __clz(d));
    }
    __syncthreads();
    u32 tmin = sc[0], shf = sc[1];

    // ---- histogram all rows, one pass, from regs ----
    #pragma unroll
    for (int t = 0; t < 18; ++t) {
        atomicAdd(&hist[(4 * q + 0) * 256 + ((kk[t][0] - tmin) >> shf)], 1u);
        atomicAdd(&hist[(4 * q + 1) * 256 + ((kk[t][1] - tmin) >> shf)], 1u);
        atomicAdd(&hist[(4 * q + 2) * 256 + ((kk[t][2] - tmin) >> shf)], 1u);
        atomicAdd(&hist[(4 * q + 3) * 256 + ((kk[t][3] - tmin) >> shf)], 1u);
    }
    __syncthreads();

    // ---- S2: per-wave suffix-scan, rows 2w and 2w+1 ----
    for (int rr = 0; rr < 2; ++rr) {
        int r = 2 * w + rr;
        u32 c0 = hist[r * 256 + lane * 4 + 0];
        u32 c1 = hist[r * 256 + lane * 4 + 1];
        u32 c2 = hist[r * 256 + lane * 4 + 2];
        u32 c3 = hist[r * 256 + lane * 4 + 3];
        u32 s3 = c3, s2 = c2 + s3, s1 = c1 + s2, s0 = c0 + s1;
        u32 suf = s0;
        #pragma unroll
        for (int off = 1; off < 64; off <<= 1) {
            u32 t2 = (u32)__shfl_down((int)suf, off);
            if (lane + off < 64) suf += t2;
        }
        u32 above_lane = suf - s0;
        u32 remK = TOPK;
        u32 sArr[4] = {s0, s1, s2, s3};
        u32 cArr[4] = {c0, c1, c2, c3};
        #pragma unroll
        for (int i = 0; i < 4; ++i) {
            u32 S = above_lane + sArr[i];
            u32 cb = cArr[i];
            if (S >= remK && S - cb < remK) {
                u32 b = lane * 4 + i;
                u32 klo = tmin + (b << shf);
                u32 khi = shf ? (klo + (1u << shf) - 1u) : klo;
                u32 above = S - cb;
                kloA[r] = klo; khiA[r] = khi; remKA[r] = remK - above; cntA[r] = cb;
                if (cb <= 64u) stateA[r] = 1u;
                else if (klo == khi) {
                    stateA[r] = 2u; TkeyA[r] = klo;
                    tieTakeA[r] = remK - above; eqCntA[r] = cb;
                } else stateA[r] = 0u;
            }
        }
    }
    __syncthreads();

    // ---- S3: rare narrowing loop (block-uniform) ----
    for (int it = 0; it < 8; ++it) {
        if (tid == 0) {
            u32 any = 0;
            for (int r = 0; r < 16; ++r) any |= (stateA[r] == 0u) ? 1u : 0u;
            sc[2] = any;
        }
        __syncthreads();
        if (!sc[2]) break;
        for (int r = 0; r < 16; ++r) {
            if (stateA[r] == 0u) {
                if (tid < 256) hist[r * 256 + tid] = 0u;
                __syncthreads();
                u32 klo = kloA[r], khi = khiA[r];
                u32 d = khi - klo;
                u32 sh2 = (d <= 255u) ? 0u : (u32)(24 - __clz(d));
                if (q == (r >> 2)) {
                    int rl = r & 3;
                    #pragma unroll
                    for (int t = 0; t < 18; ++t) {
                        u32 key = kk[t][rl];
                        if (key >= klo && key <= khi)
                            atomicAdd(&hist[r * 256 + ((key - klo) >> sh2)], 1u);
                    }
                }
                __syncthreads();
                if (w == 0) {
                    u32 c0 = hist[r * 256 + lane * 4 + 0];
                    u32 c1 = hist[r * 256 + lane * 4 + 1];
                    u32 c2 = hist[r * 256 + lane * 4 + 2];
                    u32 c3 = hist[r * 256 + lane * 4 + 3];
                    u32 s3 = c3, s2 = c2 + s3, s1 = c1 + s2, s0 = c0 + s1;
                    u32 suf = s0;
                    #pragma unroll
                    for (int off = 1; off < 64; off <<= 1) {
                        u32 t2 = (u32)__shfl_down((int)suf, off);
                        if (lane + off < 64) suf += t2;
                    }
                    u32 above_lane = suf - s0;
                    u32 remK = remKA[r];
                    u32 sArr[4] = {s0, s1, s2, s3};
                    u32 cArr[4] = {c0, c1, c2, c3};
                    #pragma unroll
                    for (int i = 0; i < 4; ++i) {
                        u32 S = above_lane + sArr[i];
                        u32 cb = cArr[i];
                        if (S >= remK && S - cb < remK) {
                            u32 b = lane * 4 + i;
                            u32 nlo = klo + (b << sh2);
                            u32 nhi = sh2 ? (nlo + (1u << sh2) - 1u) : nlo;
                            if (nhi > khi) nhi = khi;
                            u32 above = S - cb;
                            kloA[r] = nlo; khiA[r] = nhi;
                            remKA[r] = remK - above; cntA[r] = cb;
                            if (cb <= 64u) stateA[r] = 1u;
                            else if (nlo == nhi) {
                                stateA[r] = 2u; TkeyA[r] = nlo;
                                tieTakeA[r] = remK - above; eqCntA[r] = cb;
                            } else stateA[r] = 0u;
                        }
                    }
                }
                __syncthreads();
            }
        }
        __syncthreads();
    }
    if (tid < 16 && stateA[tid] == 0u) {   // unreachable safety
        stateA[tid] = 2u; TkeyA[tid] = kloA[tid];
        tieTakeA[tid] = remKA[tid]; eqCntA[tid] = cntA[tid];
    }
    __syncthreads();

    // ---- S4: collect candidates for bin-resolved rows ----
    {
        u32 st[4], kl[4], kh[4];
        #pragma unroll
        for (int r = 0; r < 4; ++r) {
            int row = 4 * q + r;
            st[r] = stateA[row]; kl[r] = kloA[row]; kh[r] = khiA[row];
        }
        #pragma unroll
        for (int t = 0; t < 18; ++t)
            #pragma unroll
            for (int r = 0; r < 4; ++r) {
                u32 key = kk[t][r];
                if (st[r] == 1u && key >= kl[r] && key <= kh[r]) {
                    int row = 4 * q + r;
                    u32 pos = atomicAdd(&candCnt[row], 1u);
                    if (pos < 64u) candk[row * 64 + pos] = key;
                }
            }
    }
    __syncthreads();

    // ---- S5: wave-parallel threshold resolution ----
    for (int rr = 0; rr < 2; ++rr) {
        int r = 2 * w + rr;
        if (stateA[r] == 1u) {
            u32 cnt = min(candCnt[r], 64u);
            u32 myk = (lane < (int)cnt) ? candk[r * 64 + lane] : 0u;
            u32 gtr = 0, eq = 0;
            for (u32 i = 0; i < cnt; ++i) {
                u32 ki = candk[r * 64 + i];
                gtr += (ki > myk) ? 1u : 0u;
                eq  += (ki == myk) ? 1u : 0u;
            }
            u32 remK = remKA[r];
            if (lane < (int)cnt && gtr < remK && remK <= gtr + eq) {
                TkeyA[r] = myk; tieTakeA[r] = remK - gtr; eqCntA[r] = eq;
            }
        }
    }
    __syncthreads();

    // ---- S6: tie cut index (stable lowest-index-first) ----
    {
        u32 T_r[4], need[4];
        #pragma unroll
        for (int r = 0; r < 4; ++r) {
            int row = 4 * q + r;
            T_r[r] = TkeyA[row];
            need[r] = (tieTakeA[row] < eqCntA[row]) ? 1u : 0u;
        }
        #pragma unroll
        for (int t = 0; t < 18; ++t)
            #pragma unroll
            for (int r = 0; r < 4; ++r) {
                if (need[r] && kk[t][r] == T_r[r]) {
                    int row = 4 * q + r;
                    u32 pos = atomicAdd(&tieCnt[row], 1u);
                    if (pos < 64u) candk[row * 64 + pos] = (u32)(w * 288 + t * 16 + cI);
                }
            }
    }
    __syncthreads();
    for (int rr = 0; rr < 2; ++rr) {
        int r = 2 * w + rr;
        if (tieTakeA[r] < eqCntA[r]) {
            u32 ec = eqCntA[r];
            if (ec <= 64u) {
                u32 mym = (lane < (int)ec) ? candk[r * 64 + lane] : 0xFFFFFFFFu;
                u32 rank = 0;
                for (u32 i = 0; i < ec; ++i)
                    rank += (candk[r * 64 + i] < mym) ? 1u : 0u;
                if (lane < (int)ec && rank == tieTakeA[r] - 1u) cutA[r] = (int)mym;
            } // ec>64: astronomically unlikely; cut stays NN-1
        }
    }
    __syncthreads();

    // ---- exp over selected; write P (bf16); per-row denominators ----
    {
        float rmaxf[4]; u32 T_r[4]; int cut_r[4];
        #pragma unroll
        for (int r = 0; r < 4; ++r) {
            int row = 4 * q + r;
            rmaxf[r] = fkey_inv(rowKmax[row]);
            T_r[r] = TkeyA[row];
            cut_r[r] = cutA[row];
        }
        float ls0 = 0.f, ls1 = 0.f, ls2 = 0.f, ls3 = 0.f;
        #pragma unroll
        for (int t = 0; t < 18; ++t) {
            int m = w * 288 + t * 16 + cI;
            {
                u32 key = kk[t][0];
                bool inc = (key > T_r[0]) || (key == T_r[0] && m <= cut_r[0]);
                float e = inc ? __expf(fkey_inv(key) - rmaxf[0]) : 0.f;
                ls0 += e; P[(4 * q + 0) * PSTR + m] = f2bf(e);
            }
            {
                u32 key = kk[t][1];
                bool inc = (key > T_r[1]) || (key == T_r[1] && m <= cut_r[1]);
                float e = inc ? __expf(fkey_inv(key) - rmaxf[1]) : 0.f;
                ls1 += e; P[(4 * q + 1) * PSTR + m] = f2bf(e);
            }
            {
                u32 key = kk[t][2];
                bool inc = (key > T_r[2]) || (key == T_r[2] && m <= cut_r[2]);
                float e = inc ? __expf(fkey_inv(key) - rmaxf[2]) : 0.f;
                ls2 += e; P[(4 * q + 2) * PSTR + m] = f2bf(e);
            }
            {
                u32 key = kk[t][3];
                bool inc = (key > T_r[3]) || (key == T_r[3] && m <= cut_r[3]);
                float e = inc ? __expf(fkey_inv(key) - rmaxf[3]) : 0.f;
                ls3 += e; P[(4 * q + 3) * PSTR + m] = f2bf(e);
            }
        }
        #pragma unroll
        for (int mk = 1; mk < 16; mk <<= 1) {
            ls0 += __shfl_xor(ls0, mk); ls1 += __shfl_xor(ls1, mk);
            ls2 += __shfl_xor(ls2, mk); ls3 += __shfl_xor(ls3, mk);
        }
        if (cI == 0) {
            atomicAdd(&denomF[4 * q + 0], ls0);
            atomicAdd(&denomF[4 * q + 1], ls1);
            atomicAdd(&denomF[4 * q + 2], ls2);
            atomicAdd(&denomF[4 * q + 3], ls3);
        }
    }
    __syncthreads();

    // ---- PV via MFMA: D[c][n] = sum_m V[c][m] * P[n][m]; wave w does its m-slice
    {
        f32x4 acc0 = {0.f, 0.f, 0.f, 0.f};
        f32x4 acc1 = {0.f, 0.f, 0.f, 0.f};
        #pragma unroll
        for (int ks = 0; ks < 9; ++ks) {
            int m0 = w * 288 + ks * 32;
            bf16x8 pf = *(const bf16x8*)(P + (size_t)cI * PSTR + m0 + q * 8);
            bf16x8 v0 = *(const bf16x8*)(Vbh + (size_t)cI * NN + m0 + q * 8);
            bf16x8 v1 = *(const bf16x8*)(Vbh + (size_t)(16 + cI) * NN + m0 + q * 8);
            acc0 = __builtin_amdgcn_mfma_f32_16x16x32_bf16(v0, pf, acc0, 0, 0, 0);
            acc1 = __builtin_amdgcn_mfma_f32_16x16x32_bf16(v1, pf, acc1, 0, 0, 0);
        }
        __syncthreads();   // P/hist region done; pvred alias safe
        #pragma unroll
        for (int r = 0; r < 4; ++r) {
            pvred[((size_t)w * 32 + (q * 4 + r)) * 16 + cI] = acc0[r];
            pvred[((size_t)w * 32 + (16 + q * 4 + r)) * 16 + cI] = acc1[r];
        }
    }
    __syncthreads();

    // ---- cross-wave reduce, scale by 1/denom, scatter to aout ----
    {
        int c = tid >> 4, n = tid & 15;
        float s = 0.f;
        #pragma unroll
        for (int w2 = 0; w2 < 8; ++w2) s += pvred[((size_t)w2 * 32 + c) * 16 + n];
        s *= (1.f / denomF[n]);
        int ng = n0 + n;
        int t = ng & 3, p = ng >> 2;
        aout[(size_t)(t * CS + h * CHD + c) * HW + p] = s;
    }
}

// ---------------------------------------------------------------------------
// Kernel 4: out = x + w_proj @ aout   (M=1024, N=576, K=1024)
// ---------------------------------------------------------------------------
#define BM 64
#define BN 64
#define BK 16
__global__ __launch_bounds__(256) void proj_kernel(
    const float* __restrict__ aout, const float* __restrict__ wproj,
    const float* __restrict__ x, float* __restrict__ out)
{
    __shared__ float As[BM][BK + 1];
    __shared__ float Bs[BK][BN + 1];
    int bx = blockIdx.x;
    int by = blockIdx.y;
    int tid = threadIdx.x;
    int tx = tid & 15, ty = tid >> 4;
    float acc[4][4] = {{0.f}};
    for (int kt = 0; kt < DIM; kt += BK) {
        #pragma unroll
        for (int i = 0; i < 4; ++i) {
            int idx = tid + i * 256;
            int r = idx >> 4, cc = idx & 15;
            As[r][cc] = wproj[(size_t)(by * BM + r) * DIM + kt + cc];
        }
        #pragma unroll
        for (int i = 0; i < 4; ++i) {
            int idx = tid + i * 256;
            int r = idx >> 6, p = idx & 63;
            Bs[r][p] = aout[(size_t)(kt + r) * HW + bx * BN + p];
        }
        __syncthreads();
        #pragma unroll
        for (int kk2 = 0; kk2 < BK; ++kk2) {
            float a[4], b[4];
            #pragma unroll
            for (int i = 0; i < 4; ++i) a[i] = As[ty * 4 + i][kk2];
            #pragma unroll
            for (int j = 0; j < 4; ++j) b[j] = Bs[kk2][tx * 4 + j];
            #pragma unroll
            for (int i = 0; i < 4; ++i)
                #pragma unroll
                for (int j = 0; j < 4; ++j) acc[i][j] += a[i] * b[j];
        }
        __syncthreads();
    }
    #pragma unroll
    for (int i = 0; i < 4; ++i) {
        int o = by * BM + ty * 4 + i;
        #pragma unroll
        for (int j = 0; j < 4; ++j) {
            int p = bx * BN + tx * 4 + j;
            out[(size_t)o * HW + p] = x[(size_t)o * HW + p] + acc[i][j];
        }
    }
}

// ---------------------------------------------------------------------------
extern "C" void kernel_launch(void* const* d_in, const int* in_sizes, int n_in,
                              void* d_out, int out_size, void* d_ws, size_t ws_size,
                              hipStream_t stream)
{
    const float* x     = (const float*)d_in[0];
    const float* temp  = (const float*)d_in[1];
    const float* w_qkv = (const float*)d_in[2];
    const float* w_dw  = (const float*)d_in[3];
    const float* wproj = (const float*)d_in[4];
    float* out = (float*)d_out;

    const size_t T = (size_t)NHEADS * CHD * NN;    // 589824
    char* ws = (char*)d_ws;
    float* qb    = (float*)(ws);                       // T f32
    float* kb    = (float*)(ws + 4 * T);               // T f32
    u16*   Qt    = (u16*)(ws + 8 * T);                 // T bf16
    u16*   Kt    = (u16*)(ws + 10 * T);                // T bf16
    u16*   Vb    = (u16*)(ws + 12 * T);                // T bf16
    float* aout  = (float*)(ws + 14 * T);              // T f32
    float* scales= (float*)(ws + 18 * T);              // 512 f32

    qkv_conv_kernel<<<256, 256, 0, stream>>>(x, w_qkv, w_dw, qb, kb, Vb);
    norm_scale_kernel<<<512, 256, 0, stream>>>(qb, kb, scales);
    transpose_cast_kernel<<<dim3(72, 8, 2), 256, 0, stream>>>(qb, kb, scales, Qt, Kt);
    attn_mfma_kernel<<<NHEADS * 144, 512, 95488, stream>>>(Qt, Kt, Vb, temp, aout);
    proj_kernel<<<dim3(9, 16), 256, 0, stream>>>(aout, wproj, x, out);
}

// Round 4
// 412.567 us; speedup vs baseline: 1.5018x; 1.5018x over previous
//
#include <hip/hip_runtime.h>
#include <math.h>

typedef unsigned int u32;
typedef unsigned short u16;
typedef __attribute__((ext_vector_type(8))) short bf16x8;
typedef __attribute__((ext_vector_type(4))) float f32x4;

#define NHEADS 8
#define HH 24
#define WW 24
#define HW 576
#define CS 256        // channels per group
#define CHD 32        // channels per head
#define NN 2304       // HW * NGROUPS
#define NGROUPS 4
#define TOPK 1843     // int(2304 * 0.8)
#define DIM 1024
#define EPSN 1e-12f

#define KSTR 2316     // keys row stride in u32 (16B aligned, bank-spread)
#define HIST_OFF (16 * KSTR)            // u32 index of hist base
#define SB_OFF   (HIST_OFF + 16 * 128)  // u32 index of small arrays
#define SMEM_BYTES ((SB_OFF + 256) * 4) // 157,440 B

__device__ __forceinline__ unsigned fkey(float f) {
    unsigned u = __float_as_uint(f);
    return u ^ ((u >> 31) ? 0xFFFFFFFFu : 0x80000000u);  // monotonic map
}
__device__ __forceinline__ float fkey_inv(unsigned k) {
    return __uint_as_float((k & 0x80000000u) ? (k ^ 0x80000000u) : ~k);
}
__device__ __forceinline__ u16 f2bf(float f) {          // RNE fp32->bf16
    unsigned u = __float_as_uint(f);
    return (u16)((u + 0x7FFFu + ((u >> 16) & 1u)) >> 16);
}

// ---------------------------------------------------------------------------
// Kernel 1: fused group-mix (w_qkv) + depthwise 3x3 conv, scatter to head
// layout q/k[h][c][n] fp32 and v[h][c][n] bf16;  n = (hh*24+ww)*4 + t
// ---------------------------------------------------------------------------
__global__ __launch_bounds__(256) void qkv_conv_kernel(
    const float* __restrict__ x, const float* __restrict__ w_qkv,
    const float* __restrict__ w_dw,
    float* __restrict__ qb, float* __restrict__ kb, u16* __restrict__ vb16)
{
    __shared__ float xp[NGROUPS][26][26];
    __shared__ float wq[48];
    __shared__ float wd[108];
    int c = blockIdx.x;          // 0..255
    int tid = threadIdx.x;

    for (int i = tid; i < NGROUPS * 26 * 26; i += 256) ((float*)xp)[i] = 0.f;
    if (tid < 48) wq[tid] = w_qkv[tid];
    if (tid < 108) wd[tid] = w_dw[tid];
    __syncthreads();
    for (int i = tid; i < NGROUPS * HW; i += 256) {
        int t = i / HW, p = i % HW;
        int hh = p / WW, ww = p % WW;
        xp[t][hh + 1][ww + 1] = x[(size_t)(t * CS + c) * HW + p];
    }
    __syncthreads();

    int hd = c >> 5, ch = c & 31;
    for (int p = tid; p < HW; p += 256) {
        int hh = p / WW, ww = p % WW;
        float res[12];
        #pragma unroll
        for (int s = 0; s < 12; ++s) {
            float acc = 0.f;
            #pragma unroll
            for (int t = 0; t < NGROUPS; ++t) {
                float cv = 0.f;
                #pragma unroll
                for (int dh = 0; dh < 3; ++dh)
                    #pragma unroll
                    for (int dw = 0; dw < 3; ++dw)
                        cv += xp[t][hh + dh][ww + dw] * wd[s * 9 + dh * 3 + dw];
                acc += wq[s * 4 + t] * cv;
            }
            res[s] = acc;
        }
        #pragma unroll
        for (int tt = 0; tt < 4; ++tt) {
            int n = p * 4 + tt;
            size_t off = ((size_t)hd * CHD + ch) * NN + n;
            qb[off] = res[tt];
            kb[off] = res[4 + tt];
            vb16[off] = f2bf(res[8 + tt]);
        }
    }
}

// ---------------------------------------------------------------------------
// Kernel 2a: per-(h,c) L2 norm reciprocal for q (b<256) and k (b>=256)
// ---------------------------------------------------------------------------
__global__ __launch_bounds__(256) void norm_scale_kernel(
    const float* __restrict__ qb, const float* __restrict__ kb,
    float* __restrict__ scales)
{
    __shared__ float redf[5];
    int b = blockIdx.x;          // 0..511
    const float* rowp = ((b < 256) ? qb : kb) + (size_t)(b & 255) * NN;
    int tid = threadIdx.x;
    float ss = 0.f;
    for (int i = tid; i < NN; i += 256) { float v = rowp[i]; ss += v * v; }
    for (int off = 32; off > 0; off >>= 1) ss += __shfl_down(ss, off);
    int wid = tid >> 6, lane = tid & 63;
    if (lane == 0) redf[wid] = ss;
    __syncthreads();
    if (tid == 0)
        scales[b] = 1.f / fmaxf(sqrtf(redf[0] + redf[1] + redf[2] + redf[3]), EPSN);
}

// ---------------------------------------------------------------------------
// Kernel 2b: transpose+scale+cast q,k: [h][c][n] fp32 -> [h][n][c] bf16
// ---------------------------------------------------------------------------
__global__ __launch_bounds__(256) void transpose_cast_kernel(
    const float* __restrict__ qb, const float* __restrict__ kb,
    const float* __restrict__ scales,
    u16* __restrict__ Qt, u16* __restrict__ Kt)
{
    __shared__ float tile[32][33];
    int ntile = blockIdx.x;        // 0..71
    int h = blockIdx.y;            // 0..7
    int which = blockIdx.z;        // 0=q 1=k
    const float* src = which ? kb : qb;
    const float* scl = scales + which * 256;
    u16* dst = which ? Kt : Qt;
    int tid = threadIdx.x;
    int n0 = ntile * 32;
    #pragma unroll
    for (int cc = 0; cc < 32; cc += 8) {
        int c = cc + (tid >> 5);
        tile[c][tid & 31] = src[(size_t)(h * CHD + c) * NN + n0 + (tid & 31)]
                            * scl[h * CHD + c];
    }
    __syncthreads();
    int cgrp = tid & 7, nrow = tid >> 3;
    #pragma unroll
    for (int c0 = 0; c0 < 32; c0 += 16) {
        int c = c0 + cgrp * 2;
        u16 v0 = f2bf(tile[c][nrow]);
        u16 v1 = f2bf(tile[c + 1][nrow]);
        ushort2 v; v.x = v0; v.y = v1;
        *(ushort2*)(dst + ((size_t)h * NN + n0 + nrow) * CHD + c) = v;
    }
}

// ---------------------------------------------------------------------------
// Kernel 3: MFMA attention, keys in LDS (no per-lane key arrays -> no spill).
// 1 block = (head, 16 rows), 512 threads = 8 waves, wave w owns cols
// [w*288,(w+1)*288). Exact top-K select via 128-bin histogram from LDS keys.
// ---------------------------------------------------------------------------
__global__ __launch_bounds__(512, 2) void attn_mfma2_kernel(
    const u16* __restrict__ Qt, const u16* __restrict__ Kt,
    const u16* __restrict__ Vb, const float* __restrict__ temp,
    float* __restrict__ aout)
{
    extern __shared__ u32 smem[];
    u32* keys    = smem;                 // [16][KSTR]
    u32* hist    = smem + HIST_OFF;      // [16][128]
    u32* candk   = hist;                 // alias (disjoint phases) [16][64]
    float* pvred = (float*)smem;         // alias keys region [8][32][16]
    u32* sb      = smem + SB_OFF;
    u32* candCnt = sb;            // [16]
    u32* tieCnt  = sb + 16;       // [16]
    u32* rowKmax = sb + 32;       // [16]
    u32* TkeyA   = sb + 48;       // [16]
    u32* tieTakeA= sb + 64;       // [16]
    u32* eqCntA  = sb + 80;       // [16]
    int* cutA    = (int*)(sb + 96);  // [16]
    u32* kloA    = sb + 112;      // [16]
    u32* khiA    = sb + 128;      // [16]
    u32* remKA   = sb + 144;      // [16]
    u32* cntA    = sb + 160;      // [16]
    u32* stateA  = sb + 176;      // [16] 0=narrow 1=bin-resolved 2=T-resolved
    float* denomF= (float*)(sb + 192); // [16]
    u32* sc      = sb + 208;      // [0]=tileMin [1]=shift [2]=anyflag

    int tid = threadIdx.x;
    int lane = tid & 63;
    int w = tid >> 6;             // wave 0..7
    int q = lane >> 4;            // lane quarter 0..3
    int cI = lane & 15;           // lane column-in-tile
    int bid = blockIdx.x;
    int h = bid / 144;
    int n0 = (bid % 144) * 16;

    if (tid < 16) {
        rowKmax[tid] = 0u; candCnt[tid] = 0u; tieCnt[tid] = 0u;
        remKA[tid] = TOPK; stateA[tid] = 0u; cutA[tid] = NN - 1;
        denomF[tid] = 0.f;
    }
    if (tid == 0) sc[0] = 0xFFFFFFFFu;
    __syncthreads();

    const u16* Qth = Qt + (size_t)h * NN * CHD;
    const u16* Kth = Kt + (size_t)h * NN * CHD;
    const u16* Vbh = Vb + (size_t)h * CHD * NN;
    float ts = temp[h];

    // ---- QK^T via MFMA; keys -> LDS ----
    {
        bf16x8 afrag = *(const bf16x8*)(Qth + (size_t)(n0 + cI) * CHD + q * 8);
        u32 lmax0 = 0, lmax1 = 0, lmax2 = 0, lmax3 = 0;
        u32 lmin = 0xFFFFFFFFu;
        #pragma unroll
        for (int t = 0; t < 18; ++t) {
            int m0 = w * 288 + t * 16;
            bf16x8 bfrag = *(const bf16x8*)(Kth + (size_t)(m0 + cI) * CHD + q * 8);
            f32x4 z = {0.f, 0.f, 0.f, 0.f};
            f32x4 acc = __builtin_amdgcn_mfma_f32_16x16x32_bf16(afrag, bfrag, z, 0, 0, 0);
            int m = m0 + cI;
            u32 k0 = fkey(acc[0] * ts); keys[(4 * q + 0) * KSTR + m] = k0;
            u32 k1 = fkey(acc[1] * ts); keys[(4 * q + 1) * KSTR + m] = k1;
            u32 k2 = fkey(acc[2] * ts); keys[(4 * q + 2) * KSTR + m] = k2;
            u32 k3 = fkey(acc[3] * ts); keys[(4 * q + 3) * KSTR + m] = k3;
            lmax0 = max(lmax0, k0); lmax1 = max(lmax1, k1);
            lmax2 = max(lmax2, k2); lmax3 = max(lmax3, k3);
            lmin = min(lmin, min(min(k0, k1), min(k2, k3)));
        }
        #pragma unroll
        for (int mk = 1; mk < 16; mk <<= 1) {
            lmax0 = max(lmax0, (u32)__shfl_xor((int)lmax0, mk));
            lmax1 = max(lmax1, (u32)__shfl_xor((int)lmax1, mk));
            lmax2 = max(lmax2, (u32)__shfl_xor((int)lmax2, mk));
            lmax3 = max(lmax3, (u32)__shfl_xor((int)lmax3, mk));
        }
        #pragma unroll
        for (int mk = 1; mk < 64; mk <<= 1)
            lmin = min(lmin, (u32)__shfl_xor((int)lmin, mk));
        if (cI == 0) {
            atomicMax(&rowKmax[4 * q + 0], lmax0);
            atomicMax(&rowKmax[4 * q + 1], lmax1);
            atomicMax(&rowKmax[4 * q + 2], lmax2);
            atomicMax(&rowKmax[4 * q + 3], lmax3);
        }
        if (lane == 0) atomicMin(&sc[0], lmin);
    }
    __syncthreads();

    // ---- zero hist; shared shift (128 bins) ----
    for (int i = tid; i < 16 * 128; i += 512) hist[i] = 0u;
    if (tid == 0) {
        u32 tmax = 0;
        for (int r = 0; r < 16; ++r) tmax = max(tmax, rowKmax[r]);
        u32 d = tmax - sc[0];
        sc[1] = (d <= 127u) ? 0u : (u32)(25 - __clz(d));
    }
    __syncthreads();
    u32 tmin = sc[0], shf = sc[1];

    // ---- histogram all rows from LDS keys ----
    for (int r = 0; r < 16; ++r)
        for (int m = tid; m < NN; m += 512) {
            u32 key = keys[r * KSTR + m];
            atomicAdd(&hist[r * 128 + ((key - tmin) >> shf)], 1u);
        }
    __syncthreads();

    // ---- S2: per-wave suffix-scan, rows 2w,2w+1 (2 bins/lane) ----
    for (int rr = 0; rr < 2; ++rr) {
        int r = 2 * w + rr;
        u32 c0 = hist[r * 128 + lane * 2 + 0];
        u32 c1 = hist[r * 128 + lane * 2 + 1];
        u32 s1 = c1, s0 = c0 + c1;
        u32 suf = s0;
        #pragma unroll
        for (int off = 1; off < 64; off <<= 1) {
            u32 t2 = (u32)__shfl_down((int)suf, off);
            if (lane + off < 64) suf += t2;
        }
        u32 above_lane = suf - s0;
        u32 remK = TOPK;
        u32 sArr[2] = {s0, s1};
        u32 cArr[2] = {c0, c1};
        #pragma unroll
        for (int i = 0; i < 2; ++i) {
            u32 S = above_lane + sArr[i];
            u32 cb = cArr[i];
            if (S >= remK && S - cb < remK) {
                u32 b = lane * 2 + i;
                u32 klo = tmin + (b << shf);
                u32 khi = shf ? (klo + (1u << shf) - 1u) : klo;
                u32 above = S - cb;
                kloA[r] = klo; khiA[r] = khi; remKA[r] = remK - above; cntA[r] = cb;
                if (cb <= 64u) stateA[r] = 1u;
                else if (klo == khi) {
                    stateA[r] = 2u; TkeyA[r] = klo;
                    tieTakeA[r] = remK - above; eqCntA[r] = cb;
                } else stateA[r] = 0u;
            }
        }
    }
    __syncthreads();

    // ---- S3: rare narrowing loop (block-uniform) ----
    for (int it = 0; it < 8; ++it) {
        if (tid == 0) {
            u32 any = 0;
            for (int r = 0; r < 16; ++r) any |= (stateA[r] == 0u) ? 1u : 0u;
            sc[2] = any;
        }
        __syncthreads();
        if (!sc[2]) break;
        for (int r = 0; r < 16; ++r) {
            if (stateA[r] == 0u) {
                if (tid < 128) hist[r * 128 + tid] = 0u;
                __syncthreads();
                u32 klo = kloA[r], khi = khiA[r];
                u32 d = khi - klo;
                u32 sh2 = (d <= 127u) ? 0u : (u32)(25 - __clz(d));
                for (int m = tid; m < NN; m += 512) {
                    u32 key = keys[r * KSTR + m];
                    if (key >= klo && key <= khi)
                        atomicAdd(&hist[r * 128 + ((key - klo) >> sh2)], 1u);
                }
                __syncthreads();
                if (w == 0) {
                    u32 c0 = hist[r * 128 + lane * 2 + 0];
                    u32 c1 = hist[r * 128 + lane * 2 + 1];
                    u32 s1 = c1, s0 = c0 + c1;
                    u32 suf = s0;
                    #pragma unroll
                    for (int off = 1; off < 64; off <<= 1) {
                        u32 t2 = (u32)__shfl_down((int)suf, off);
                        if (lane + off < 64) suf += t2;
                    }
                    u32 above_lane = suf - s0;
                    u32 remK = remKA[r];
                    u32 sArr[2] = {s0, s1};
                    u32 cArr[2] = {c0, c1};
                    #pragma unroll
                    for (int i = 0; i < 2; ++i) {
                        u32 S = above_lane + sArr[i];
                        u32 cb = cArr[i];
                        if (S >= remK && S - cb < remK) {
                            u32 b = lane * 2 + i;
                            u32 nlo = klo + (b << sh2);
                            u32 nhi = sh2 ? (nlo + (1u << sh2) - 1u) : nlo;
                            if (nhi > khi) nhi = khi;
                            u32 above = S - cb;
                            kloA[r] = nlo; khiA[r] = nhi;
                            remKA[r] = remK - above; cntA[r] = cb;
                            if (cb <= 64u) stateA[r] = 1u;
                            else if (nlo == nhi) {
                                stateA[r] = 2u; TkeyA[r] = nlo;
                                tieTakeA[r] = remK - above; eqCntA[r] = cb;
                            } else stateA[r] = 0u;
                        }
                    }
                }
                __syncthreads();
            }
        }
        __syncthreads();
    }
    if (tid < 16 && stateA[tid] == 0u) {   // unreachable safety
        stateA[tid] = 2u; TkeyA[tid] = kloA[tid];
        tieTakeA[tid] = remKA[tid]; eqCntA[tid] = cntA[tid];
    }
    __syncthreads();

    // ---- S4: collect candidate keys for bin-resolved rows ----
    for (int r = 0; r < 16; ++r) {
        if (stateA[r] == 1u) {
            u32 kl = kloA[r], kh = khiA[r];
            for (int m = tid; m < NN; m += 512) {
                u32 key = keys[r * KSTR + m];
                if (key >= kl && key <= kh) {
                    u32 pos = atomicAdd(&candCnt[r], 1u);
                    if (pos < 64u) candk[r * 64 + pos] = key;
                }
            }
        }
    }
    __syncthreads();

    // ---- S5: wave-parallel threshold resolution ----
    for (int rr = 0; rr < 2; ++rr) {
        int r = 2 * w + rr;
        if (stateA[r] == 1u) {
            u32 cnt = min(candCnt[r], 64u);
            u32 myk = (lane < (int)cnt) ? candk[r * 64 + lane] : 0u;
            u32 gtr = 0, eq = 0;
            for (u32 i = 0; i < cnt; ++i) {
                u32 ki = candk[r * 64 + i];
                gtr += (ki > myk) ? 1u : 0u;
                eq  += (ki == myk) ? 1u : 0u;
            }
            u32 remK = remKA[r];
            if (lane < (int)cnt && gtr < remK && remK <= gtr + eq) {
                TkeyA[r] = myk; tieTakeA[r] = remK - gtr; eqCntA[r] = eq;
            }
        }
    }
    __syncthreads();

    // ---- S6: tie cut index (stable lowest-index-first) ----
    for (int r = 0; r < 16; ++r) {
        if (tieTakeA[r] < eqCntA[r]) {
            u32 T = TkeyA[r];
            for (int m = tid; m < NN; m += 512)
                if (keys[r * KSTR + m] == T) {
                    u32 pos = atomicAdd(&tieCnt[r], 1u);
                    if (pos < 64u) candk[r * 64 + pos] = (u32)m;
                }
        }
    }
    __syncthreads();
    for (int rr = 0; rr < 2; ++rr) {
        int r = 2 * w + rr;
        if (tieTakeA[r] < eqCntA[r]) {
            u32 ec = eqCntA[r];
            if (ec <= 64u) {
                u32 mym = (lane < (int)ec) ? candk[r * 64 + lane] : 0xFFFFFFFFu;
                u32 rank = 0;
                for (u32 i = 0; i < ec; ++i)
                    rank += (candk[r * 64 + i] < mym) ? 1u : 0u;
                if (lane < (int)ec && rank == tieTakeA[r] - 1u) cutA[r] = (int)mym;
            }
        }
    }
    __syncthreads();

    // ---- exp over selected; write bf16 P in-place into key slots ----
    for (int r = 0; r < 16; ++r) {
        float rmax = fkey_inv(rowKmax[r]);
        u32 T = TkeyA[r];
        int cut = cutA[r];
        float ls = 0.f;
        for (int m = tid; m < NN; m += 512) {
            u32 key = keys[r * KSTR + m];
            bool inc = (key > T) || (key == T && m <= cut);
            float e = inc ? __expf(fkey_inv(key) - rmax) : 0.f;
            keys[r * KSTR + m] = (u32)f2bf(e);
            ls += e;
        }
        #pragma unroll
        for (int off = 32; off > 0; off >>= 1) ls += __shfl_down(ls, off);
        if (lane == 0) atomicAdd(&denomF[r], ls);
    }
    __syncthreads();

    // ---- PV via MFMA: D[c][n] = sum_m V[c][m] * P[n][m] ----
    {
        f32x4 acc0 = {0.f, 0.f, 0.f, 0.f};
        f32x4 acc1 = {0.f, 0.f, 0.f, 0.f};
        #pragma unroll
        for (int ks = 0; ks < 9; ++ks) {
            int m0 = w * 288 + ks * 32;
            const u32* kp = keys + (size_t)cI * KSTR + m0 + q * 8;
            uint4 A = *(const uint4*)(kp);
            uint4 B = *(const uint4*)(kp + 4);
            u32 w0 = (A.x & 0xFFFFu) | (A.y << 16);
            u32 w1 = (A.z & 0xFFFFu) | (A.w << 16);
            u32 w2 = (B.x & 0xFFFFu) | (B.y << 16);
            u32 w3 = (B.z & 0xFFFFu) | (B.w << 16);
            union { u32 u[4]; bf16x8 v; } pk;
            pk.u[0] = w0; pk.u[1] = w1; pk.u[2] = w2; pk.u[3] = w3;
            bf16x8 v0 = *(const bf16x8*)(Vbh + (size_t)cI * NN + m0 + q * 8);
            bf16x8 v1 = *(const bf16x8*)(Vbh + (size_t)(16 + cI) * NN + m0 + q * 8);
            acc0 = __builtin_amdgcn_mfma_f32_16x16x32_bf16(v0, pk.v, acc0, 0, 0, 0);
            acc1 = __builtin_amdgcn_mfma_f32_16x16x32_bf16(v1, pk.v, acc1, 0, 0, 0);
        }
        __syncthreads();   // keys region done; pvred alias safe
        #pragma unroll
        for (int r = 0; r < 4; ++r) {
            pvred[((size_t)w * 32 + (q * 4 + r)) * 16 + cI] = acc0[r];
            pvred[((size_t)w * 32 + (16 + q * 4 + r)) * 16 + cI] = acc1[r];
        }
    }
    __syncthreads();

    // ---- cross-wave reduce, scale by 1/denom, scatter to aout ----
    {
        int c = tid >> 4, n = tid & 15;
        float s = 0.f;
        #pragma unroll
        for (int w2 = 0; w2 < 8; ++w2) s += pvred[((size_t)w2 * 32 + c) * 16 + n];
        s *= (1.f / denomF[n]);
        int ng = n0 + n;
        int t = ng & 3, p = ng >> 2;
        aout[(size_t)(t * CS + h * CHD + c) * HW + p] = s;
    }
}

// ---------------------------------------------------------------------------
// Kernel 4: out = x + w_proj @ aout   (M=1024, N=576, K=1024)
// ---------------------------------------------------------------------------
#define BM 64
#define BN 64
#define BK 16
__global__ __launch_bounds__(256) void proj_kernel(
    const float* __restrict__ aout, const float* __restrict__ wproj,
    const float* __restrict__ x, float* __restrict__ out)
{
    __shared__ float As[BM][BK + 1];
    __shared__ float Bs[BK][BN + 1];
    int bx = blockIdx.x;
    int by = blockIdx.y;
    int tid = threadIdx.x;
    int tx = tid & 15, ty = tid >> 4;
    float acc[4][4] = {{0.f}};
    for (int kt = 0; kt < DIM; kt += BK) {
        #pragma unroll
        for (int i = 0; i < 4; ++i) {
            int idx = tid + i * 256;
            int r = idx >> 4, cc = idx & 15;
            As[r][cc] = wproj[(size_t)(by * BM + r) * DIM + kt + cc];
        }
        #pragma unroll
        for (int i = 0; i < 4; ++i) {
            int idx = tid + i * 256;
            int r = idx >> 6, p = idx & 63;
            Bs[r][p] = aout[(size_t)(kt + r) * HW + bx * BN + p];
        }
        __syncthreads();
        #pragma unroll
        for (int kk2 = 0; kk2 < BK; ++kk2) {
            float a[4], b[4];
            #pragma unroll
            for (int i = 0; i < 4; ++i) a[i] = As[ty * 4 + i][kk2];
            #pragma unroll
            for (int j = 0; j < 4; ++j) b[j] = Bs[kk2][tx * 4 + j];
            #pragma unroll
            for (int i = 0; i < 4; ++i)
                #pragma unroll
                for (int j = 0; j < 4; ++j) acc[i][j] += a[i] * b[j];
        }
        __syncthreads();
    }
    #pragma unroll
    for (int i = 0; i < 4; ++i) {
        int o = by * BM + ty * 4 + i;
        #pragma unroll
        for (int j = 0; j < 4; ++j) {
            int p = bx * BN + tx * 4 + j;
            out[(size_t)o * HW + p] = x[(size_t)o * HW + p] + acc[i][j];
        }
    }
}

// ---------------------------------------------------------------------------
extern "C" void kernel_launch(void* const* d_in, const int* in_sizes, int n_in,
                              void* d_out, int out_size, void* d_ws, size_t ws_size,
                              hipStream_t stream)
{
    const float* x     = (const float*)d_in[0];
    const float* temp  = (const float*)d_in[1];
    const float* w_qkv = (const float*)d_in[2];
    const float* w_dw  = (const float*)d_in[3];
    const float* wproj = (const float*)d_in[4];
    float* out = (float*)d_out;

    const size_t T = (size_t)NHEADS * CHD * NN;    // 589824
    char* ws = (char*)d_ws;
    float* qb    = (float*)(ws);                       // T f32
    float* kb    = (float*)(ws + 4 * T);               // T f32
    u16*   Qt    = (u16*)(ws + 8 * T);                 // T bf16
    u16*   Kt    = (u16*)(ws + 10 * T);                // T bf16
    u16*   Vb    = (u16*)(ws + 12 * T);                // T bf16
    float* aout  = (float*)(ws + 14 * T);              // T f32
    float* scales= (float*)(ws + 18 * T);              // 512 f32

    qkv_conv_kernel<<<256, 256, 0, stream>>>(x, w_qkv, w_dw, qb, kb, Vb);
    norm_scale_kernel<<<512, 256, 0, stream>>>(qb, kb, scales);
    transpose_cast_kernel<<<dim3(72, 8, 2), 256, 0, stream>>>(qb, kb, scales, Qt, Kt);
    attn_mfma2_kernel<<<NHEADS * 144, 512, SMEM_BYTES, stream>>>(Qt, Kt, Vb, temp, aout);
    proj_kernel<<<dim3(9, 16), 256, 0, stream>>>(aout, wproj, x, out);
}

// Round 5
// 281.256 us; speedup vs baseline: 2.2029x; 1.4669x over previous
//
#include <hip/hip_runtime.h>
#include <math.h>

typedef unsigned int u32;
typedef unsigned short u16;
typedef __attribute__((ext_vector_type(8))) short bf16x8;
typedef __attribute__((ext_vector_type(4))) float f32x4;

#define NHEADS 8
#define HH 24
#define WW 24
#define HW 576
#define CS 256        // channels per group
#define CHD 32        // channels per head
#define NN 2304       // HW * NGROUPS
#define NGROUPS 4
#define TOPK 1843     // int(2304 * 0.8)
#define DIM 1024
#define EPSN 1e-12f

__device__ __forceinline__ u32 fkey(float f) {
    u32 u = __float_as_uint(f);
    return u ^ ((u >> 31) ? 0xFFFFFFFFu : 0x80000000u);  // monotonic map
}
__device__ __forceinline__ float fkey_inv(u32 k) {
    return __uint_as_float((k & 0x80000000u) ? (k ^ 0x80000000u) : ~k);
}
__device__ __forceinline__ u16 f2bf(float f) {          // RNE fp32->bf16
    u32 u = __float_as_uint(f);
    return (u16)((u + 0x7FFFu + ((u >> 16) & 1u)) >> 16);
}
__device__ __forceinline__ int binOf(float s, float its) {
    int b = (int)(__builtin_fmaf(s, its, 1.0f) * 128.0f);
    return min(max(b, 0), 255);
}

// ---------------------------------------------------------------------------
// Kernel 1: fused group-mix (w_qkv) + depthwise 3x3 conv, scatter to head
// layout q/k[h][c][n] fp32 and v[h][c][n] bf16;  n = (hh*24+ww)*4 + t
// ---------------------------------------------------------------------------
__global__ __launch_bounds__(256) void qkv_conv_kernel(
    const float* __restrict__ x, const float* __restrict__ w_qkv,
    const float* __restrict__ w_dw,
    float* __restrict__ qb, float* __restrict__ kb, u16* __restrict__ vb16)
{
    __shared__ float xp[NGROUPS][26][26];
    __shared__ float wq[48];
    __shared__ float wd[108];
    int c = blockIdx.x;          // 0..255
    int tid = threadIdx.x;

    for (int i = tid; i < NGROUPS * 26 * 26; i += 256) ((float*)xp)[i] = 0.f;
    if (tid < 48) wq[tid] = w_qkv[tid];
    if (tid < 108) wd[tid] = w_dw[tid];
    __syncthreads();
    for (int i = tid; i < NGROUPS * HW; i += 256) {
        int t = i / HW, p = i % HW;
        int hh = p / WW, ww = p % WW;
        xp[t][hh + 1][ww + 1] = x[(size_t)(t * CS + c) * HW + p];
    }
    __syncthreads();

    int hd = c >> 5, ch = c & 31;
    for (int p = tid; p < HW; p += 256) {
        int hh = p / WW, ww = p % WW;
        float res[12];
        #pragma unroll
        for (int s = 0; s < 12; ++s) {
            float acc = 0.f;
            #pragma unroll
            for (int t = 0; t < NGROUPS; ++t) {
                float cv = 0.f;
                #pragma unroll
                for (int dh = 0; dh < 3; ++dh)
                    #pragma unroll
                    for (int dw = 0; dw < 3; ++dw)
                        cv += xp[t][hh + dh][ww + dw] * wd[s * 9 + dh * 3 + dw];
                acc += wq[s * 4 + t] * cv;
            }
            res[s] = acc;
        }
        #pragma unroll
        for (int tt = 0; tt < 4; ++tt) {
            int n = p * 4 + tt;
            size_t off = ((size_t)hd * CHD + ch) * NN + n;
            qb[off] = res[tt];
            kb[off] = res[4 + tt];
            vb16[off] = f2bf(res[8 + tt]);
        }
    }
}

// ---------------------------------------------------------------------------
// Kernel 2a: per-(h,c) L2 norm reciprocal for q (b<256) and k (b>=256)
// ---------------------------------------------------------------------------
__global__ __launch_bounds__(256) void norm_scale_kernel(
    const float* __restrict__ qb, const float* __restrict__ kb,
    float* __restrict__ scales)
{
    __shared__ float redf[5];
    int b = blockIdx.x;          // 0..511
    const float* rowp = ((b < 256) ? qb : kb) + (size_t)(b & 255) * NN;
    int tid = threadIdx.x;
    float ss = 0.f;
    for (int i = tid; i < NN; i += 256) { float v = rowp[i]; ss += v * v; }
    for (int off = 32; off > 0; off >>= 1) ss += __shfl_down(ss, off);
    int wid = tid >> 6, lane = tid & 63;
    if (lane == 0) redf[wid] = ss;
    __syncthreads();
    if (tid == 0)
        scales[b] = 1.f / fmaxf(sqrtf(redf[0] + redf[1] + redf[2] + redf[3]), EPSN);
}

// ---------------------------------------------------------------------------
// Kernel 2b: transpose+scale+cast q,k: [h][c][n] fp32 -> [h][n][c] bf16
// ---------------------------------------------------------------------------
__global__ __launch_bounds__(256) void transpose_cast_kernel(
    const float* __restrict__ qb, const float* __restrict__ kb,
    const float* __restrict__ scales,
    u16* __restrict__ Qt, u16* __restrict__ Kt)
{
    __shared__ float tile[32][33];
    int ntile = blockIdx.x;        // 0..71
    int h = blockIdx.y;            // 0..7
    int which = blockIdx.z;        // 0=q 1=k
    const float* src = which ? kb : qb;
    const float* scl = scales + which * 256;
    u16* dst = which ? Kt : Qt;
    int tid = threadIdx.x;
    int n0 = ntile * 32;
    #pragma unroll
    for (int cc = 0; cc < 32; cc += 8) {
        int c = cc + (tid >> 5);
        tile[c][tid & 31] = src[(size_t)(h * CHD + c) * NN + n0 + (tid & 31)]
                            * scl[h * CHD + c];
    }
    __syncthreads();
    int cgrp = tid & 7, nrow = tid >> 3;
    #pragma unroll
    for (int c0 = 0; c0 < 32; c0 += 16) {
        int c = c0 + cgrp * 2;
        u16 v0 = f2bf(tile[c][nrow]);
        u16 v1 = f2bf(tile[c + 1][nrow]);
        ushort2 v; v.x = v0; v.y = v1;
        *(ushort2*)(dst + ((size_t)h * NN + n0 + nrow) * CHD + c) = v;
    }
}

// ---------------------------------------------------------------------------
// Kernel 2c: cast w_proj fp32 -> bf16
// ---------------------------------------------------------------------------
__global__ __launch_bounds__(256) void cast_wproj_kernel(
    const float* __restrict__ wp, u16* __restrict__ wpb)
{
    int i = blockIdx.x * 256 + threadIdx.x;   // DIM*DIM/4 elems of float4
    float4 v = ((const float4*)wp)[i];
    ushort4 o;
    o.x = f2bf(v.x); o.y = f2bf(v.y); o.z = f2bf(v.z); o.w = f2bf(v.w);
    ((ushort4*)wpb)[i] = o;
}

// ---------------------------------------------------------------------------
// Kernel 3: fused MFMA attention with recompute-based exact top-K.
// Block = (head, 16 rows), 256 threads = 4 waves; wave w owns m-strip
// [w*576,(w+1)*576). Scores are NEVER stored: each selection phase re-runs
// the QK^T MFMA pass (trivial FLOPs). ~30 KB LDS -> 5-6 blocks/CU.
// ---------------------------------------------------------------------------
__global__ __launch_bounds__(256, 4) void attn_fused_kernel(
    const u16* __restrict__ Qt, const u16* __restrict__ Kt,
    const u16* __restrict__ Vb, const float* __restrict__ temp,
    u16* __restrict__ aoutT)
{
    __shared__ u32 hist[16][256];      // 16 KB; aliased as red[4][32][16] f32 in epilogue
    __shared__ u32 candK[16][64];      // 4 KB
    __shared__ u32 candM[16][64];      // 4 KB
    __shared__ u16 Pst[4][16][40];     // 5 KB per-wave P staging
    __shared__ u32 selBin[16], kloA[16], khiA[16], remKA[16],
                   stateA[16], TkeyA[16], maxkA[16], candCnt[16];
    __shared__ int cutA[16];
    __shared__ float denomF[16];
    __shared__ u32 flagS;

    int tid = threadIdx.x;
    int lane = tid & 63;
    int w = tid >> 6;            // wave 0..3
    int q = lane >> 4;           // quarter 0..3
    int cI = lane & 15;
    int bid = blockIdx.x;
    int h = bid / 144;
    int n0 = (bid % 144) * 16;

    for (int i = tid; i < 16 * 256; i += 256) ((u32*)hist)[i] = 0u;
    if (tid < 16) {
        maxkA[tid] = 0u; candCnt[tid] = 0u; denomF[tid] = 0.f;
        stateA[tid] = 0u; cutA[tid] = NN - 1; remKA[tid] = TOPK;
        kloA[tid] = 0u; khiA[tid] = 0xFFFFFFFFu; TkeyA[tid] = 0u; selBin[tid] = 0u;
    }
    __syncthreads();

    const u16* Qth = Qt + (size_t)h * NN * CHD;
    const u16* Kth = Kt + (size_t)h * NN * CHD;
    const u16* Vbh = Vb + (size_t)h * CHD * NN;
    float ts = temp[h];
    float its = 1.f / fmaxf(fabsf(ts), 1e-30f);

    bf16x8 afrag = *(const bf16x8*)(Qth + (size_t)(n0 + cI) * CHD + q * 8);
    int mW = w * 576;
    const f32x4 zz = {0.f, 0.f, 0.f, 0.f};

    // ---- P1: hist (fixed-range float bins) + row max ----
    {
        u32 lmax[4] = {0u, 0u, 0u, 0u};
        #pragma unroll 4
        for (int t = 0; t < 36; ++t) {
            bf16x8 bfrag = *(const bf16x8*)(Kth + (size_t)(mW + t * 16 + cI) * CHD + q * 8);
            f32x4 a = __builtin_amdgcn_mfma_f32_16x16x32_bf16(afrag, bfrag, zz, 0, 0, 0);
            #pragma unroll
            for (int r = 0; r < 4; ++r) {
                float s = a[r] * ts;
                u32 k = fkey(s);
                lmax[r] = max(lmax[r], k);
                atomicAdd(&hist[4 * q + r][binOf(s, its)], 1u);
            }
        }
        #pragma unroll
        for (int r = 0; r < 4; ++r) {
            #pragma unroll
            for (int mk = 1; mk < 16; mk <<= 1)
                lmax[r] = max(lmax[r], (u32)__shfl_xor((int)lmax[r], mk));
            if (cI == 0) atomicMax(&maxkA[4 * q + r], lmax[r]);
        }
    }
    __syncthreads();

    // ---- initial scan: find bin containing the TOPK-th ----
    #pragma unroll
    for (int rr = 0; rr < 4; ++rr) {
        int r = 4 * w + rr;
        uint4 c4 = *((const uint4*)&hist[r][lane * 4]);
        u32 s3 = c4.w, s2 = c4.z + s3, s1 = c4.y + s2, s0 = c4.x + s1;
        u32 suf = s0;
        #pragma unroll
        for (int off = 1; off < 64; off <<= 1) {
            u32 t2 = (u32)__shfl_down((int)suf, off);
            if (lane + off < 64) suf += t2;
        }
        u32 above_lane = suf - s0;
        u32 sArr[4] = {s0, s1, s2, s3};
        u32 cArr[4] = {c4.x, c4.y, c4.z, c4.w};
        #pragma unroll
        for (int i = 0; i < 4; ++i) {
            u32 S = above_lane + sArr[i];
            u32 cb = cArr[i];
            if (S >= TOPK && S - cb < TOPK) {
                selBin[r] = lane * 4 + i;
                remKA[r] = TOPK - (S - cb);
                stateA[r] = (cb <= 64u) ? 1u : 0u;
            }
        }
    }
    __syncthreads();

    // ---- narrowing rounds (rare: bin count > 64) ----
    for (int round = 0; round < 4; ++round) {
        if (tid == 0) {
            u32 any = 0;
            for (int r = 0; r < 16; ++r) any |= (stateA[r] == 0u) ? 1u : 0u;
            flagS = any;
        }
        __syncthreads();
        if (!flagS) break;
        for (int r = 0; r < 16; ++r)
            if (stateA[r] == 0u) hist[r][tid & 255] = 0u;
        __syncthreads();
        #pragma unroll 4
        for (int t = 0; t < 36; ++t) {
            bf16x8 bfrag = *(const bf16x8*)(Kth + (size_t)(mW + t * 16 + cI) * CHD + q * 8);
            f32x4 a = __builtin_amdgcn_mfma_f32_16x16x32_bf16(afrag, bfrag, zz, 0, 0, 0);
            #pragma unroll
            for (int r = 0; r < 4; ++r) {
                int row = 4 * q + r;
                if (stateA[row] == 0u) {
                    float s = a[r] * ts;
                    u32 k = fkey(s);
                    u32 klo = kloA[row], khi = khiA[row];
                    if (binOf(s, its) == (int)selBin[row] && k >= klo && k <= khi) {
                        u32 range = khi - klo;
                        int sh = (range > 255u) ? (24 - __clz(range)) : 0;
                        atomicAdd(&hist[row][(k - klo) >> sh], 1u);
                    }
                }
            }
        }
        __syncthreads();
        #pragma unroll
        for (int rr = 0; rr < 4; ++rr) {
            int r = 4 * w + rr;
            if (stateA[r] != 0u) continue;
            u32 klo = kloA[r], khi = khiA[r];
            u32 range = khi - klo;
            int sh = (range > 255u) ? (24 - __clz(range)) : 0;
            uint4 c4 = *((const uint4*)&hist[r][lane * 4]);
            u32 s3 = c4.w, s2 = c4.z + s3, s1 = c4.y + s2, s0 = c4.x + s1;
            u32 suf = s0;
            #pragma unroll
            for (int off = 1; off < 64; off <<= 1) {
                u32 t2 = (u32)__shfl_down((int)suf, off);
                if (lane + off < 64) suf += t2;
            }
            u32 above_lane = suf - s0;
            u32 remK = remKA[r];
            u32 sArr[4] = {s0, s1, s2, s3};
            u32 cArr[4] = {c4.x, c4.y, c4.z, c4.w};
            #pragma unroll
            for (int i = 0; i < 4; ++i) {
                u32 S = above_lane + sArr[i];
                u32 cb = cArr[i];
                if (S >= remK && S - cb < remK) {
                    u32 b = lane * 4 + i;
                    u32 nlo = klo + (b << sh);
                    unsigned long long nhiL =
                        (unsigned long long)klo + (((unsigned long long)(b + 1)) << sh) - 1ull;
                    u32 nhi = (nhiL > (unsigned long long)khi) ? khi : (u32)nhiL;
                    remKA[r] = remK - (S - cb);
                    kloA[r] = nlo; khiA[r] = nhi;
                    if (cb <= 64u) stateA[r] = 1u;
                    else if (nlo == nhi) {            // >64 exact ties: give up on cut
                        TkeyA[r] = nlo; cutA[r] = NN - 1; stateA[r] = 3u;
                    } else stateA[r] = 0u;
                }
            }
        }
        __syncthreads();
    }
    if (tid < 16 && stateA[tid] == 0u) {   // unreachable safety
        TkeyA[tid] = kloA[tid]; cutA[tid] = NN - 1; stateA[tid] = 3u;
    }
    __syncthreads();

    // ---- P2: candidate collection (recompute pass) ----
    #pragma unroll 4
    for (int t = 0; t < 36; ++t) {
        bf16x8 bfrag = *(const bf16x8*)(Kth + (size_t)(mW + t * 16 + cI) * CHD + q * 8);
        f32x4 a = __builtin_amdgcn_mfma_f32_16x16x32_bf16(afrag, bfrag, zz, 0, 0, 0);
        int m = mW + t * 16 + cI;
        #pragma unroll
        for (int r = 0; r < 4; ++r) {
            int row = 4 * q + r;
            if (stateA[row] == 1u) {
                float s = a[r] * ts;
                u32 k = fkey(s);
                if (binOf(s, its) == (int)selBin[row] &&
                    k >= kloA[row] && k <= khiA[row]) {
                    u32 pos = atomicAdd(&candCnt[row], 1u);
                    if (pos < 64u) { candK[row][pos] = k; candM[row][pos] = (u32)m; }
                }
            }
        }
    }
    __syncthreads();

    // ---- resolve: rank-remK by (key desc, index asc) -> T and cut ----
    #pragma unroll
    for (int rr = 0; rr < 4; ++rr) {
        int r = 4 * w + rr;
        if (stateA[r] == 1u) {
            u32 cnt = min(candCnt[r], 64u);
            u32 remK = remKA[r];
            u32 myk = 0u, mym = 0u;
            if (lane < (int)cnt) { myk = candK[r][lane]; mym = candM[r][lane]; }
            u32 gtr = 0;
            for (u32 i = 0; i < cnt; ++i) {
                u32 ki = candK[r][i], mi = candM[r][i];
                gtr += (ki > myk || (ki == myk && mi < mym)) ? 1u : 0u;
            }
            if (lane < (int)cnt && gtr == remK - 1u) {
                TkeyA[r] = myk; cutA[r] = (int)mym;
            }
        }
    }
    __syncthreads();

    // ---- P3: recompute -> masked exp -> P bf16 (wave-local LDS) -> PV MFMA ----
    {
        float maxf[4], ls[4];
        u32 Tr[4]; int cutr[4];
        #pragma unroll
        for (int r = 0; r < 4; ++r) {
            int row = 4 * q + r;
            maxf[r] = fkey_inv(maxkA[row]);
            Tr[r] = TkeyA[row];
            cutr[r] = cutA[row];
            ls[r] = 0.f;
        }
        f32x4 acc0 = {0.f, 0.f, 0.f, 0.f};
        f32x4 acc1 = {0.f, 0.f, 0.f, 0.f};
        for (int j = 0; j < 18; ++j) {
            int mb = mW + j * 32;
            bf16x8 b0 = *(const bf16x8*)(Kth + (size_t)(mb + cI) * CHD + q * 8);
            bf16x8 b1 = *(const bf16x8*)(Kth + (size_t)(mb + 16 + cI) * CHD + q * 8);
            f32x4 a0 = __builtin_amdgcn_mfma_f32_16x16x32_bf16(afrag, b0, zz, 0, 0, 0);
            f32x4 a1 = __builtin_amdgcn_mfma_f32_16x16x32_bf16(afrag, b1, zz, 0, 0, 0);
            #pragma unroll
            for (int r = 0; r < 4; ++r) {
                {
                    float s = a0[r] * ts;
                    u32 k = fkey(s);
                    int m = mb + cI;
                    bool inc = (k > Tr[r]) || (k == Tr[r] && m <= cutr[r]);
                    float p = inc ? __expf(s - maxf[r]) : 0.f;
                    ls[r] += p;
                    Pst[w][4 * q + r][cI] = f2bf(p);
                }
                {
                    float s = a1[r] * ts;
                    u32 k = fkey(s);
                    int m = mb + 16 + cI;
                    bool inc = (k > Tr[r]) || (k == Tr[r] && m <= cutr[r]);
                    float p = inc ? __expf(s - maxf[r]) : 0.f;
                    ls[r] += p;
                    Pst[w][4 * q + r][16 + cI] = f2bf(p);
                }
            }
            bf16x8 pf = *(const bf16x8*)&Pst[w][cI][q * 8];
            bf16x8 v0 = *(const bf16x8*)(Vbh + (size_t)cI * NN + mb + q * 8);
            bf16x8 v1 = *(const bf16x8*)(Vbh + (size_t)(16 + cI) * NN + mb + q * 8);
            acc0 = __builtin_amdgcn_mfma_f32_16x16x32_bf16(v0, pf, acc0, 0, 0, 0);
            acc1 = __builtin_amdgcn_mfma_f32_16x16x32_bf16(v1, pf, acc1, 0, 0, 0);
        }
        #pragma unroll
        for (int r = 0; r < 4; ++r) {
            #pragma unroll
            for (int mk = 1; mk < 16; mk <<= 1)
                ls[r] += __shfl_xor(ls[r], mk);
            if (cI == 0) atomicAdd(&denomF[4 * q + r], ls[r]);
        }
        // stage partial PV into red (aliases hist; hist dead now)
        float* red = (float*)hist;           // [4][32][16]
        #pragma unroll
        for (int r = 0; r < 4; ++r) {
            red[((size_t)w * 32 + (4 * q + r)) * 16 + cI] = acc0[r];
            red[((size_t)w * 32 + 16 + (4 * q + r)) * 16 + cI] = acc1[r];
        }
    }
    __syncthreads();

    // ---- epilogue: cross-wave reduce, normalize, store bf16 aout^T ----
    {
        const float* red = (const float*)hist;
        #pragma unroll
        for (int k2 = 0; k2 < 2; ++k2) {
            int idx = tid + k2 * 256;
            int c = idx >> 4, n = idx & 15;
            float s = red[(0 * 32 + c) * 16 + n] + red[(1 * 32 + c) * 16 + n]
                    + red[(2 * 32 + c) * 16 + n] + red[(3 * 32 + c) * 16 + n];
            s /= denomF[n];
            int ng = n0 + n;
            int t = ng & 3, p = ng >> 2;
            aoutT[(size_t)p * DIM + t * CS + h * CHD + c] = f2bf(s);
        }
    }
}

// ---------------------------------------------------------------------------
// Kernel 4: out = x + w_proj @ attn_out via bf16 MFMA.
// A = wproj_bf16[o][c], B = aoutT[p][c] (k=c contiguous). Tile 64o x 16p.
// ---------------------------------------------------------------------------
__global__ __launch_bounds__(256) void proj_mfma_kernel(
    const u16* __restrict__ aoutT, const u16* __restrict__ wpb,
    const float* __restrict__ x, float* __restrict__ out)
{
    int tid = threadIdx.x, lane = tid & 63, w = tid >> 6;
    int q = lane >> 4, cI = lane & 15;
    int p0 = blockIdx.x * 16;
    int o0 = blockIdx.y * 64 + w * 16;
    f32x4 acc = {0.f, 0.f, 0.f, 0.f};
    const u16* arow = wpb + (size_t)(o0 + cI) * DIM + q * 8;
    const u16* brow = aoutT + (size_t)(p0 + cI) * DIM + q * 8;
    #pragma unroll 8
    for (int k = 0; k < DIM; k += 32) {
        bf16x8 af = *(const bf16x8*)(arow + k);
        bf16x8 bf = *(const bf16x8*)(brow + k);
        acc = __builtin_amdgcn_mfma_f32_16x16x32_bf16(af, bf, acc, 0, 0, 0);
    }
    #pragma unroll
    for (int r = 0; r < 4; ++r) {
        int o = o0 + 4 * q + r, p = p0 + cI;
        out[(size_t)o * HW + p] = x[(size_t)o * HW + p] + acc[r];
    }
}

// ---------------------------------------------------------------------------
extern "C" void kernel_launch(void* const* d_in, const int* in_sizes, int n_in,
                              void* d_out, int out_size, void* d_ws, size_t ws_size,
                              hipStream_t stream)
{
    const float* x     = (const float*)d_in[0];
    const float* temp  = (const float*)d_in[1];
    const float* w_qkv = (const float*)d_in[2];
    const float* w_dw  = (const float*)d_in[3];
    const float* wproj = (const float*)d_in[4];
    float* out = (float*)d_out;

    const size_t T = (size_t)NHEADS * CHD * NN;    // 589824
    char* ws = (char*)d_ws;
    float* qb    = (float*)(ws);                   // T f32
    float* kb    = (float*)(ws + 4 * T);           // T f32
    u16*   Qt    = (u16*)(ws + 8 * T);             // T bf16
    u16*   Kt    = (u16*)(ws + 10 * T);            // T bf16
    u16*   Vb    = (u16*)(ws + 12 * T);            // T bf16
    u16*   aoutT = (u16*)(ws + 14 * T);            // HW*DIM bf16 (= 2T bytes)
    u16*   wpb   = (u16*)(ws + 16 * T);            // DIM*DIM bf16 (2 MB)
    float* scales= (float*)(ws + 16 * T + (size_t)DIM * DIM * 2);  // 512 f32

    qkv_conv_kernel<<<256, 256, 0, stream>>>(x, w_qkv, w_dw, qb, kb, Vb);
    norm_scale_kernel<<<512, 256, 0, stream>>>(qb, kb, scales);
    transpose_cast_kernel<<<dim3(72, 8, 2), 256, 0, stream>>>(qb, kb, scales, Qt, Kt);
    cast_wproj_kernel<<<DIM * DIM / 4 / 256, 256, 0, stream>>>(wproj, wpb);
    attn_fused_kernel<<<NHEADS * 144, 256, 0, stream>>>(Qt, Kt, Vb, temp, aoutT);
    proj_mfma_kernel<<<dim3(36, 16), 256, 0, stream>>>(aoutT, wpb, x, out);
}

// Round 6
// 181.252 us; speedup vs baseline: 3.4183x; 1.5517x over previous
//
#include <hip/hip_runtime.h>
#include <math.h>

typedef unsigned int u32;
typedef unsigned long long u64;
typedef unsigned short u16;
typedef __attribute__((ext_vector_type(8))) short bf16x8;
typedef __attribute__((ext_vector_type(4))) float f32x4;

#define NHEADS 8
#define HH 24
#define WW 24
#define HW 576
#define CS 256        // channels per group
#define CHD 32        // channels per head
#define NN 2304       // HW * NGROUPS
#define NGROUPS 4
#define TOPK 1843     // int(2304 * 0.8)
#define DIM 1024
#define EPSN 1e-12f

__device__ __forceinline__ u32 fkey(float f) {
    u32 u = __float_as_uint(f);
    return u ^ ((u >> 31) ? 0xFFFFFFFFu : 0x80000000u);  // monotonic map
}
__device__ __forceinline__ float fkey_inv(u32 k) {
    return __uint_as_float((k & 0x80000000u) ? (k ^ 0x80000000u) : ~k);
}
__device__ __forceinline__ u16 f2bf(float f) {          // RNE fp32->bf16
    u32 u = __float_as_uint(f);
    return (u16)((u + 0x7FFFu + ((u >> 16) & 1u)) >> 16);
}

// ---------------------------------------------------------------------------
// Kernel 1: fused group-mix (w_qkv) + depthwise 3x3 conv, scatter to head
// layout q/k[h][c][n] fp32 and v[h][c][n] bf16;  n = (hh*24+ww)*4 + t
// ---------------------------------------------------------------------------
__global__ __launch_bounds__(256) void qkv_conv_kernel(
    const float* __restrict__ x, const float* __restrict__ w_qkv,
    const float* __restrict__ w_dw,
    float* __restrict__ qb, float* __restrict__ kb, u16* __restrict__ vb16)
{
    __shared__ float xp[NGROUPS][26][26];
    __shared__ float wq[48];
    __shared__ float wd[108];
    int c = blockIdx.x;          // 0..255
    int tid = threadIdx.x;

    for (int i = tid; i < NGROUPS * 26 * 26; i += 256) ((float*)xp)[i] = 0.f;
    if (tid < 48) wq[tid] = w_qkv[tid];
    if (tid < 108) wd[tid] = w_dw[tid];
    __syncthreads();
    for (int i = tid; i < NGROUPS * HW; i += 256) {
        int t = i / HW, p = i % HW;
        int hh = p / WW, ww = p % WW;
        xp[t][hh + 1][ww + 1] = x[(size_t)(t * CS + c) * HW + p];
    }
    __syncthreads();

    int hd = c >> 5, ch = c & 31;
    for (int p = tid; p < HW; p += 256) {
        int hh = p / WW, ww = p % WW;
        float res[12];
        #pragma unroll
        for (int s = 0; s < 12; ++s) {
            float acc = 0.f;
            #pragma unroll
            for (int t = 0; t < NGROUPS; ++t) {
                float cv = 0.f;
                #pragma unroll
                for (int dh = 0; dh < 3; ++dh)
                    #pragma unroll
                    for (int dw = 0; dw < 3; ++dw)
                        cv += xp[t][hh + dh][ww + dw] * wd[s * 9 + dh * 3 + dw];
                acc += wq[s * 4 + t] * cv;
            }
            res[s] = acc;
        }
        #pragma unroll
        for (int tt = 0; tt < 4; ++tt) {
            int n = p * 4 + tt;
            size_t off = ((size_t)hd * CHD + ch) * NN + n;
            qb[off] = res[tt];
            kb[off] = res[4 + tt];
            vb16[off] = f2bf(res[8 + tt]);
        }
    }
}

// ---------------------------------------------------------------------------
// Kernel 2a: per-(h,c) L2 norm reciprocal for q (b<256) and k (b>=256)
// ---------------------------------------------------------------------------
__global__ __launch_bounds__(256) void norm_scale_kernel(
    const float* __restrict__ qb, const float* __restrict__ kb,
    float* __restrict__ scales)
{
    __shared__ float redf[5];
    int b = blockIdx.x;          // 0..511
    const float* rowp = ((b < 256) ? qb : kb) + (size_t)(b & 255) * NN;
    int tid = threadIdx.x;
    float ss = 0.f;
    for (int i = tid; i < NN; i += 256) { float v = rowp[i]; ss += v * v; }
    for (int off = 32; off > 0; off >>= 1) ss += __shfl_down(ss, off);
    int wid = tid >> 6, lane = tid & 63;
    if (lane == 0) redf[wid] = ss;
    __syncthreads();
    if (tid == 0)
        scales[b] = 1.f / fmaxf(sqrtf(redf[0] + redf[1] + redf[2] + redf[3]), EPSN);
}

// ---------------------------------------------------------------------------
// Kernel 2b: transpose+scale+cast q,k: [h][c][n] fp32 -> [h][n][c] bf16
// ---------------------------------------------------------------------------
__global__ __launch_bounds__(256) void transpose_cast_kernel(
    const float* __restrict__ qb, const float* __restrict__ kb,
    const float* __restrict__ scales,
    u16* __restrict__ Qt, u16* __restrict__ Kt)
{
    __shared__ float tile[32][33];
    int ntile = blockIdx.x;        // 0..71
    int h = blockIdx.y;            // 0..7
    int which = blockIdx.z;        // 0=q 1=k
    const float* src = which ? kb : qb;
    const float* scl = scales + which * 256;
    u16* dst = which ? Kt : Qt;
    int tid = threadIdx.x;
    int n0 = ntile * 32;
    #pragma unroll
    for (int cc = 0; cc < 32; cc += 8) {
        int c = cc + (tid >> 5);
        tile[c][tid & 31] = src[(size_t)(h * CHD + c) * NN + n0 + (tid & 31)]
                            * scl[h * CHD + c];
    }
    __syncthreads();
    int cgrp = tid & 7, nrow = tid >> 3;
    #pragma unroll
    for (int c0 = 0; c0 < 32; c0 += 16) {
        int c = c0 + cgrp * 2;
        u16 v0 = f2bf(tile[c][nrow]);
        u16 v1 = f2bf(tile[c + 1][nrow]);
        ushort2 v; v.x = v0; v.y = v1;
        *(ushort2*)(dst + ((size_t)h * NN + n0 + nrow) * CHD + c) = v;
    }
}

// ---------------------------------------------------------------------------
// Kernel 2c: cast w_proj fp32 -> bf16
// ---------------------------------------------------------------------------
__global__ __launch_bounds__(256) void cast_wproj_kernel(
    const float* __restrict__ wp, u16* __restrict__ wpb)
{
    int i = blockIdx.x * 256 + threadIdx.x;   // DIM*DIM/4 elems of float4
    float4 v = ((const float4*)wp)[i];
    ushort4 o;
    o.x = f2bf(v.x); o.y = f2bf(v.y); o.z = f2bf(v.z); o.w = f2bf(v.w);
    ((ushort4*)wpb)[i] = o;
}

// ---------------------------------------------------------------------------
// Kernel 3: fused MFMA attention, recompute-based exact top-K with
// ADAPTIVE per-row key-range histogram (conflict-light).
// Block = (head, 16 rows), 512 threads = 8 waves; wave w owns m-strip
// [w*288,(w+1)*288). Scores never stored; 4 MFMA passes total (typ.).
// ---------------------------------------------------------------------------
__global__ __launch_bounds__(512, 2) void attn_fused2_kernel(
    const u16* __restrict__ Qt, const u16* __restrict__ Kt,
    const u16* __restrict__ Vb, const float* __restrict__ temp,
    u16* __restrict__ aoutT)
{
    __shared__ u32 hist[256][16];      // [bin][row] 16 KB; alias red f32[8][32][16]
    __shared__ u32 candK[16][64];      // 4 KB
    __shared__ u32 candM[16][64];      // 4 KB
    __shared__ u16 Pst[8][16][40];     // 10 KB per-wave P staging
    __shared__ u32 kminA[16], maxkA[16], shA[16], kloA[16], khiA[16],
                   remKA[16], stateA[16], TkeyA[16], candCnt[16];
    __shared__ int cutA[16];
    __shared__ float denomF[16];
    __shared__ u32 flagS;

    int tid = threadIdx.x;
    int lane = tid & 63;
    int w = tid >> 6;            // wave 0..7
    int q = lane >> 4;           // quarter 0..3
    int cI = lane & 15;
    int h = blockIdx.x / 144;
    int n0 = (blockIdx.x % 144) * 16;

    for (int i = tid; i < 256 * 16; i += 512) ((u32*)hist)[i] = 0u;
    if (tid < 16) {
        kminA[tid] = 0xFFFFFFFFu; maxkA[tid] = 0u; candCnt[tid] = 0u;
        denomF[tid] = 0.f; stateA[tid] = 0u; cutA[tid] = NN - 1;
        remKA[tid] = TOPK; TkeyA[tid] = 0u;
    }
    __syncthreads();

    const u16* Qth = Qt + (size_t)h * NN * CHD;
    const u16* Kth = Kt + (size_t)h * NN * CHD;
    const u16* Vbh = Vb + (size_t)h * CHD * NN;
    float ts = temp[h];

    bf16x8 afrag = *(const bf16x8*)(Qth + (size_t)(n0 + cI) * CHD + q * 8);
    int mW = w * 288;
    const f32x4 zz = {0.f, 0.f, 0.f, 0.f};

    // ---- P0: exact per-row key min/max (shuffle-only reduce) ----
    {
        u32 lmin[4], lmax[4];
        #pragma unroll
        for (int r = 0; r < 4; ++r) { lmin[r] = 0xFFFFFFFFu; lmax[r] = 0u; }
        #pragma unroll 2
        for (int t = 0; t < 18; ++t) {
            bf16x8 bfrag = *(const bf16x8*)(Kth + (size_t)(mW + t * 16 + cI) * CHD + q * 8);
            f32x4 a = __builtin_amdgcn_mfma_f32_16x16x32_bf16(afrag, bfrag, zz, 0, 0, 0);
            #pragma unroll
            for (int r = 0; r < 4; ++r) {
                u32 k = fkey(a[r] * ts);
                lmin[r] = min(lmin[r], k); lmax[r] = max(lmax[r], k);
            }
        }
        #pragma unroll
        for (int r = 0; r < 4; ++r) {
            #pragma unroll
            for (int mk = 1; mk < 16; mk <<= 1) {
                lmin[r] = min(lmin[r], (u32)__shfl_xor((int)lmin[r], mk));
                lmax[r] = max(lmax[r], (u32)__shfl_xor((int)lmax[r], mk));
            }
            if (cI == 0) {
                atomicMin(&kminA[4 * q + r], lmin[r]);
                atomicMax(&maxkA[4 * q + r], lmax[r]);
            }
        }
    }
    __syncthreads();
    if (tid < 16) {
        u32 range = maxkA[tid] - kminA[tid];
        shA[tid] = (range > 255u) ? (u32)(24 - __clz(range)) : 0u;
    }
    __syncthreads();

    // ---- P1: adaptive histogram (keys spread ~9/bin) ----
    {
        u32 km[4], sh[4];
        #pragma unroll
        for (int r = 0; r < 4; ++r) { km[r] = kminA[4 * q + r]; sh[r] = shA[4 * q + r]; }
        #pragma unroll 2
        for (int t = 0; t < 18; ++t) {
            bf16x8 bfrag = *(const bf16x8*)(Kth + (size_t)(mW + t * 16 + cI) * CHD + q * 8);
            f32x4 a = __builtin_amdgcn_mfma_f32_16x16x32_bf16(afrag, bfrag, zz, 0, 0, 0);
            #pragma unroll
            for (int r = 0; r < 4; ++r) {
                u32 k = fkey(a[r] * ts);
                atomicAdd(&hist[(k - km[r]) >> sh[r]][4 * q + r], 1u);
            }
        }
    }
    __syncthreads();

    // ---- initial scan: per wave rows 2w, 2w+1 ----
    #pragma unroll
    for (int rr = 0; rr < 2; ++rr) {
        int r = 2 * w + rr;
        u32 c0 = hist[lane * 4 + 0][r];
        u32 c1 = hist[lane * 4 + 1][r];
        u32 c2 = hist[lane * 4 + 2][r];
        u32 c3 = hist[lane * 4 + 3][r];
        u32 s3 = c3, s2 = c2 + s3, s1 = c1 + s2, s0 = c0 + s1;
        u32 suf = s0;
        #pragma unroll
        for (int off = 1; off < 64; off <<= 1) {
            u32 t2 = (u32)__shfl_down((int)suf, off);
            if (lane + off < 64) suf += t2;
        }
        u32 above_lane = suf - s0;
        u32 sArr[4] = {s0, s1, s2, s3};
        u32 cArr[4] = {c0, c1, c2, c3};
        u32 km = kminA[r], sh = shA[r];
        #pragma unroll
        for (int i = 0; i < 4; ++i) {
            u32 S = above_lane + sArr[i];
            u32 cb = cArr[i];
            if (S >= TOPK && S - cb < TOPK) {
                u32 b = lane * 4 + i;
                u32 klo = km + (b << sh);
                u64 khiL = (u64)km + ((u64)(b + 1) << sh) - 1ull;
                u32 khi = (khiL > 0xFFFFFFFFull) ? 0xFFFFFFFFu : (u32)khiL;
                kloA[r] = klo; khiA[r] = khi;
                remKA[r] = TOPK - (S - cb);
                if (cb <= 64u) stateA[r] = 1u;
                else if (klo == khi) { stateA[r] = 3u; TkeyA[r] = klo; }
                else stateA[r] = 0u;
            }
        }
    }
    __syncthreads();

    // ---- narrowing rounds (rare) ----
    for (int round = 0; round < 4; ++round) {
        if (tid == 0) {
            u32 any = 0;
            for (int r = 0; r < 16; ++r) any |= (stateA[r] == 0u) ? 1u : 0u;
            flagS = any;
        }
        __syncthreads();
        if (!flagS) break;
        if (tid < 256) {
            for (int r = 0; r < 16; ++r)
                if (stateA[r] == 0u) hist[tid][r] = 0u;
        }
        __syncthreads();
        {
            u32 st[4], kl[4], kh[4], s2h[4];
            #pragma unroll
            for (int r = 0; r < 4; ++r) {
                int row = 4 * q + r;
                st[r] = stateA[row]; kl[r] = kloA[row]; kh[r] = khiA[row];
                u32 rg = kh[r] - kl[r];
                s2h[r] = (rg > 255u) ? (u32)(24 - __clz(rg)) : 0u;
            }
            #pragma unroll 2
            for (int t = 0; t < 18; ++t) {
                bf16x8 bfrag = *(const bf16x8*)(Kth + (size_t)(mW + t * 16 + cI) * CHD + q * 8);
                f32x4 a = __builtin_amdgcn_mfma_f32_16x16x32_bf16(afrag, bfrag, zz, 0, 0, 0);
                #pragma unroll
                for (int r = 0; r < 4; ++r) {
                    if (st[r] == 0u) {
                        u32 k = fkey(a[r] * ts);
                        if (k >= kl[r] && k <= kh[r])
                            atomicAdd(&hist[(k - kl[r]) >> s2h[r]][4 * q + r], 1u);
                    }
                }
            }
        }
        __syncthreads();
        #pragma unroll
        for (int rr = 0; rr < 2; ++rr) {
            int r = 2 * w + rr;
            if (stateA[r] != 0u) continue;
            u32 klo = kloA[r], khi = khiA[r];
            u32 rg = khi - klo;
            u32 sh = (rg > 255u) ? (u32)(24 - __clz(rg)) : 0u;
            u32 c0 = hist[lane * 4 + 0][r];
            u32 c1 = hist[lane * 4 + 1][r];
            u32 c2 = hist[lane * 4 + 2][r];
            u32 c3 = hist[lane * 4 + 3][r];
            u32 s3 = c3, s2 = c2 + s3, s1 = c1 + s2, s0 = c0 + s1;
            u32 suf = s0;
            #pragma unroll
            for (int off = 1; off < 64; off <<= 1) {
                u32 t2 = (u32)__shfl_down((int)suf, off);
                if (lane + off < 64) suf += t2;
            }
            u32 above_lane = suf - s0;
            u32 remK = remKA[r];
            u32 sArr[4] = {s0, s1, s2, s3};
            u32 cArr[4] = {c0, c1, c2, c3};
            #pragma unroll
            for (int i = 0; i < 4; ++i) {
                u32 S = above_lane + sArr[i];
                u32 cb = cArr[i];
                if (S >= remK && S - cb < remK) {
                    u32 b = lane * 4 + i;
                    u32 nlo = klo + (b << sh);
                    u64 nhiL = (u64)klo + ((u64)(b + 1) << sh) - 1ull;
                    u32 nhi = (nhiL > (u64)khi) ? khi : (u32)nhiL;
                    kloA[r] = nlo; khiA[r] = nhi;
                    remKA[r] = remK - (S - cb);
                    if (cb <= 64u) stateA[r] = 1u;
                    else if (nlo == nhi) { stateA[r] = 3u; TkeyA[r] = nlo; }
                    else stateA[r] = 0u;
                }
            }
        }
        __syncthreads();
    }
    if (tid < 16 && stateA[tid] == 0u) {   // unreachable safety
        TkeyA[tid] = kloA[tid]; stateA[tid] = 3u;
    }
    __syncthreads();

    // ---- P2: candidate collection ----
    {
        u32 st[4], kl[4], kh[4];
        #pragma unroll
        for (int r = 0; r < 4; ++r) {
            int row = 4 * q + r;
            st[r] = stateA[row]; kl[r] = kloA[row]; kh[r] = khiA[row];
        }
        #pragma unroll 2
        for (int t = 0; t < 18; ++t) {
            bf16x8 bfrag = *(const bf16x8*)(Kth + (size_t)(mW + t * 16 + cI) * CHD + q * 8);
            f32x4 a = __builtin_amdgcn_mfma_f32_16x16x32_bf16(afrag, bfrag, zz, 0, 0, 0);
            int m = mW + t * 16 + cI;
            #pragma unroll
            for (int r = 0; r < 4; ++r) {
                if (st[r] == 1u) {
                    u32 k = fkey(a[r] * ts);
                    if (k >= kl[r] && k <= kh[r]) {
                        int row = 4 * q + r;
                        u32 pos = atomicAdd(&candCnt[row], 1u);
                        if (pos < 64u) { candK[row][pos] = k; candM[row][pos] = (u32)m; }
                    }
                }
            }
        }
    }
    __syncthreads();

    // ---- resolve: rank remK-th by (key desc, index asc) -> T, cut ----
    #pragma unroll
    for (int rr = 0; rr < 2; ++rr) {
        int r = 2 * w + rr;
        if (stateA[r] == 1u) {
            u32 cnt = min(candCnt[r], 64u);
            u32 remK = remKA[r];
            u32 myk = 0u, mym = 0u;
            if (lane < (int)cnt) { myk = candK[r][lane]; mym = candM[r][lane]; }
            u32 gtr = 0;
            for (u32 i = 0; i < cnt; ++i) {
                u32 ki = candK[r][i], mi = candM[r][i];
                gtr += (ki > myk || (ki == myk && mi < mym)) ? 1u : 0u;
            }
            if (lane < (int)cnt && gtr == remK - 1u) {
                TkeyA[r] = myk; cutA[r] = (int)mym;
            }
        }
    }
    __syncthreads();

    // ---- P3: recompute -> masked exp -> P bf16 -> PV MFMA ----
    {
        float maxf[4], ls[4];
        u32 Tr[4]; int cutr[4];
        #pragma unroll
        for (int r = 0; r < 4; ++r) {
            int row = 4 * q + r;
            maxf[r] = fkey_inv(maxkA[row]);
            Tr[r] = TkeyA[row];
            cutr[r] = cutA[row];
            ls[r] = 0.f;
        }
        f32x4 acc0 = {0.f, 0.f, 0.f, 0.f};
        f32x4 acc1 = {0.f, 0.f, 0.f, 0.f};
        for (int j = 0; j < 9; ++j) {
            int mb = mW + j * 32;
            bf16x8 b0 = *(const bf16x8*)(Kth + (size_t)(mb + cI) * CHD + q * 8);
            bf16x8 b1 = *(const bf16x8*)(Kth + (size_t)(mb + 16 + cI) * CHD + q * 8);
            f32x4 a0 = __builtin_amdgcn_mfma_f32_16x16x32_bf16(afrag, b0, zz, 0, 0, 0);
            f32x4 a1 = __builtin_amdgcn_mfma_f32_16x16x32_bf16(afrag, b1, zz, 0, 0, 0);
            #pragma unroll
            for (int r = 0; r < 4; ++r) {
                {
                    float s = a0[r] * ts;
                    u32 k = fkey(s);
                    int m = mb + cI;
                    bool inc = (k > Tr[r]) || (k == Tr[r] && m <= cutr[r]);
                    float p = inc ? __expf(s - maxf[r]) : 0.f;
                    ls[r] += p;
                    Pst[w][4 * q + r][cI] = f2bf(p);
                }
                {
                    float s = a1[r] * ts;
                    u32 k = fkey(s);
                    int m = mb + 16 + cI;
                    bool inc = (k > Tr[r]) || (k == Tr[r] && m <= cutr[r]);
                    float p = inc ? __expf(s - maxf[r]) : 0.f;
                    ls[r] += p;
                    Pst[w][4 * q + r][16 + cI] = f2bf(p);
                }
            }
            bf16x8 pf = *(const bf16x8*)&Pst[w][cI][q * 8];
            bf16x8 v0 = *(const bf16x8*)(Vbh + (size_t)cI * NN + mb + q * 8);
            bf16x8 v1 = *(const bf16x8*)(Vbh + (size_t)(16 + cI) * NN + mb + q * 8);
            acc0 = __builtin_amdgcn_mfma_f32_16x16x32_bf16(v0, pf, acc0, 0, 0, 0);
            acc1 = __builtin_amdgcn_mfma_f32_16x16x32_bf16(v1, pf, acc1, 0, 0, 0);
        }
        #pragma unroll
        for (int r = 0; r < 4; ++r) {
            #pragma unroll
            for (int mk = 1; mk < 16; mk <<= 1)
                ls[r] += __shfl_xor(ls[r], mk);
            if (cI == 0) atomicAdd(&denomF[4 * q + r], ls[r]);
        }
        __syncthreads();              // hist dead -> red alias safe
        float* red = (float*)hist;    // [8][32][16]
        #pragma unroll
        for (int r = 0; r < 4; ++r) {
            red[((size_t)w * 32 + (4 * q + r)) * 16 + cI] = acc0[r];
            red[((size_t)w * 32 + 16 + (4 * q + r)) * 16 + cI] = acc1[r];
        }
    }
    __syncthreads();

    // ---- epilogue: cross-wave reduce, normalize, store bf16 aout^T ----
    {
        const float* red = (const float*)hist;
        int c = tid >> 4, n = tid & 15;
        float s = 0.f;
        #pragma unroll
        for (int w2 = 0; w2 < 8; ++w2) s += red[((size_t)w2 * 32 + c) * 16 + n];
        s /= denomF[n];
        int ng = n0 + n;
        int t = ng & 3, p = ng >> 2;
        aoutT[(size_t)p * DIM + t * CS + h * CHD + c] = f2bf(s);
    }
}

// ---------------------------------------------------------------------------
// Kernel 4: out = x + w_proj @ attn_out via bf16 MFMA.
// A = wproj_bf16[o][c], B = aoutT[p][c] (k=c contiguous). Tile 64o x 16p.
// ---------------------------------------------------------------------------
__global__ __launch_bounds__(256) void proj_mfma_kernel(
    const u16* __restrict__ aoutT, const u16* __restrict__ wpb,
    const float* __restrict__ x, float* __restrict__ out)
{
    int tid = threadIdx.x, lane = tid & 63, w = tid >> 6;
    int q = lane >> 4, cI = lane & 15;
    int p0 = blockIdx.x * 16;
    int o0 = blockIdx.y * 64 + w * 16;
    f32x4 acc = {0.f, 0.f, 0.f, 0.f};
    const u16* arow = wpb + (size_t)(o0 + cI) * DIM + q * 8;
    const u16* brow = aoutT + (size_t)(p0 + cI) * DIM + q * 8;
    #pragma unroll 8
    for (int k = 0; k < DIM; k += 32) {
        bf16x8 af = *(const bf16x8*)(arow + k);
        bf16x8 bf = *(const bf16x8*)(brow + k);
        acc = __builtin_amdgcn_mfma_f32_16x16x32_bf16(af, bf, acc, 0, 0, 0);
    }
    #pragma unroll
    for (int r = 0; r < 4; ++r) {
        int o = o0 + 4 * q + r, p = p0 + cI;
        out[(size_t)o * HW + p] = x[(size_t)o * HW + p] + acc[r];
    }
}

// ---------------------------------------------------------------------------
extern "C" void kernel_launch(void* const* d_in, const int* in_sizes, int n_in,
                              void* d_out, int out_size, void* d_ws, size_t ws_size,
                              hipStream_t stream)
{
    const float* x     = (const float*)d_in[0];
    const float* temp  = (const float*)d_in[1];
    const float* w_qkv = (const float*)d_in[2];
    const float* w_dw  = (const float*)d_in[3];
    const float* wproj = (const float*)d_in[4];
    float* out = (float*)d_out;

    const size_t T = (size_t)NHEADS * CHD * NN;    // 589824
    char* ws = (char*)d_ws;
    float* qb    = (float*)(ws);                   // T f32
    float* kb    = (float*)(ws + 4 * T);           // T f32
    u16*   Qt    = (u16*)(ws + 8 * T);             // T bf16
    u16*   Kt    = (u16*)(ws + 10 * T);            // T bf16
    u16*   Vb    = (u16*)(ws + 12 * T);            // T bf16
    u16*   aoutT = (u16*)(ws + 14 * T);            // HW*DIM bf16 (= 2T bytes)
    u16*   wpb   = (u16*)(ws + 16 * T);            // DIM*DIM bf16 (2 MB)
    float* scales= (float*)(ws + 16 * T + (size_t)DIM * DIM * 2);  // 512 f32

    qkv_conv_kernel<<<256, 256, 0, stream>>>(x, w_qkv, w_dw, qb, kb, Vb);
    norm_scale_kernel<<<512, 256, 0, stream>>>(qb, kb, scales);
    transpose_cast_kernel<<<dim3(72, 8, 2), 256, 0, stream>>>(qb, kb, scales, Qt, Kt);
    cast_wproj_kernel<<<DIM * DIM / 4 / 256, 256, 0, stream>>>(wproj, wpb);
    attn_fused2_kernel<<<NHEADS * 144, 512, 0, stream>>>(Qt, Kt, Vb, temp, aoutT);
    proj_mfma_kernel<<<dim3(36, 16), 256, 0, stream>>>(aoutT, wpb, x, out);
}